// Round 1
// baseline (343.187 us; speedup 1.0000x reference)
//
#include <hip/hip_runtime.h>

#define SEQ   2048
#define NHEADS 16
#define HDIM  64
#define HID   1024
#define ROT   32

typedef __attribute__((ext_vector_type(8))) short  short8;
typedef __attribute__((ext_vector_type(4))) float  floatx4;

__device__ __forceinline__ ushort f2bf(float f) {
    union { float f; uint u; } v; v.f = f;
    uint x = v.u;
    uint r = (x + 0x7FFFu + ((x >> 16) & 1u)) >> 16;
    return (ushort)r;
}

__device__ __forceinline__ floatx4 mfma_bf16(short8 a, short8 b, floatx4 c) {
    return __builtin_amdgcn_mfma_f32_16x16x32_bf16(a, b, c, 0, 0, 0);
}

// ---------------------------------------------------------------------------
// Kernel 1: qkv = hidden @ w_qkv  (M=4096, N=3072, K=1024), fused RoPE +
// head split. Writes Q,K,V as bf16 in (b, h, s, d) layout.
// ---------------------------------------------------------------------------
__global__ __launch_bounds__(256) void qkv_rope_kernel(
    const float* __restrict__ hidden,   // (4096, 1024)
    const float* __restrict__ wqkv,     // (1024, 3072)
    ushort* __restrict__ Qb, ushort* __restrict__ Kb, ushort* __restrict__ Vb)
{
    __shared__ ushort Al[128 * 40];   // A tile, rows x k, stride 40 (80B, 16B-aligned rows)
    __shared__ ushort Bl[128 * 40];   // B^T tile, cols x k
    const int tid  = threadIdx.x;
    const int lane = tid & 63;
    const int wv   = tid >> 6;
    const int g    = lane >> 4;
    const int l15  = lane & 15;
    const int m0 = blockIdx.y * 128;
    const int n0 = blockIdx.x * 128;
    const int wr = (wv >> 1) * 64;
    const int wc = (wv & 1) * 64;

    floatx4 acc[4][4];
    #pragma unroll
    for (int a = 0; a < 4; a++)
        #pragma unroll
        for (int bq = 0; bq < 4; bq++)
            acc[a][bq] = floatx4{0.f, 0.f, 0.f, 0.f};

    for (int k0 = 0; k0 < 1024; k0 += 32) {
        // stage A: 128 rows x 32 k (fp32 -> bf16)
        #pragma unroll
        for (int i = 0; i < 4; i++) {
            int idx = tid + 256 * i;
            int row = idx >> 3;
            int kc  = (idx & 7) << 2;
            const float4 v = *(const float4*)(hidden + (size_t)(m0 + row) * 1024 + k0 + kc);
            uint2 u;
            u.x = (uint)f2bf(v.x) | ((uint)f2bf(v.y) << 16);
            u.y = (uint)f2bf(v.z) | ((uint)f2bf(v.w) << 16);
            *(uint2*)&Al[row * 40 + kc] = u;
        }
        // stage B transposed: Bl[n][k] = wqkv[k][n]
        #pragma unroll
        for (int i = 0; i < 4; i++) {
            int idx = tid + 256 * i;
            int n   = idx & 127;
            int kq  = idx >> 7;   // 0..7 -> k chunk of 4
            const float* src = wqkv + (size_t)(k0 + kq * 4) * 3072 + n0 + n;
            float a0 = src[0];
            float a1 = src[3072];
            float a2 = src[6144];
            float a3 = src[9216];
            uint2 u;
            u.x = (uint)f2bf(a0) | ((uint)f2bf(a1) << 16);
            u.y = (uint)f2bf(a2) | ((uint)f2bf(a3) << 16);
            *(uint2*)&Bl[n * 40 + kq * 4] = u;
        }
        __syncthreads();
        short8 af[4], bfr[4];
        #pragma unroll
        for (int fm = 0; fm < 4; fm++)
            af[fm] = *(const short8*)&Al[(wr + fm * 16 + l15) * 40 + g * 8];
        #pragma unroll
        for (int fn = 0; fn < 4; fn++)
            bfr[fn] = *(const short8*)&Bl[(wc + fn * 16 + l15) * 40 + g * 8];
        #pragma unroll
        for (int fm = 0; fm < 4; fm++)
            #pragma unroll
            for (int fn = 0; fn < 4; fn++)
                acc[fm][fn] = mfma_bf16(af[fm], bfr[fn], acc[fm][fn]);
        __syncthreads();
    }

    // epilogue: RoPE + scatter into Q/K/V (b,h,s,d) bf16
    #pragma unroll
    for (int fn = 0; fn < 4; fn++) {
        const int c    = n0 + wc + fn * 16 + l15;     // qkv column, 0..3071
        const int mp   = c / 384;
        const int rem  = c - mp * 384;
        const int tsel = rem >> 7;                    // 0=q 1=k 2=v
        const int j    = (rem >> 6) & 1;
        const int d    = rem & 63;
        const int head = mp * 2 + j;
        ushort* basep = (tsel == 0) ? Qb : (tsel == 1) ? Kb : Vb;
        const bool rope = (tsel < 2) && (d < ROT);
        float freq = 0.f;
        if (rope) {
            // 10000^(-(d/2)/16) = 2^(-(d/2) * log2(10000)/16)
            freq = exp2f((float)(d >> 1) * -0.830482023721841f);
        }
        #pragma unroll
        for (int fm = 0; fm < 4; fm++) {
            #pragma unroll
            for (int r = 0; r < 4; r++) {
                int row = m0 + wr + fm * 16 + g * 4 + r;  // global M index
                int bb  = row >> 11;
                int s   = row & 2047;
                float val = acc[fm][fn][r];
                float pv  = __shfl_xor(val, 1, 64);       // RoPE pair partner
                float outv = val;
                if (rope) {
                    float ang = (float)s * freq;
                    float sn, cs;
                    sincosf(ang, &sn, &cs);
                    outv = ((d & 1) == 0) ? (val * cs - pv * sn)
                                          : (val * cs + pv * sn);
                }
                basep[((size_t)(bb * NHEADS + head) * SEQ + s) * HDIM + d] = f2bf(outv);
            }
        }
    }
}

// ---------------------------------------------------------------------------
// Kernel 2: flash attention, causal. 1 WG = 64 q-rows of one (b,h).
// 4 waves x 16 q-rows each; KV tiles of 32 keys. Writes attn (b,s,h*64+d) bf16.
// ---------------------------------------------------------------------------
__global__ __launch_bounds__(256) void attn_kernel(
    const ushort* __restrict__ Qb, const ushort* __restrict__ Kb,
    const ushort* __restrict__ Vb, ushort* __restrict__ attn)
{
    __shared__ ushort Ql[64 * 72];        // q rows, stride 72 (144B)
    __shared__ ushort Kl[32 * 72];        // keys, stride 72
    __shared__ ushort Vt[64 * 40];        // Vt[d][key], stride 40
    __shared__ ushort Pl[4 * 16 * 40];    // per-wave P, [q][key], stride 40

    const int tid  = threadIdx.x;
    const int lane = tid & 63;
    const int wv   = tid >> 6;
    const int g    = lane >> 4;
    const int l15  = lane & 15;
    const int qb = blockIdx.x, hh = blockIdx.y, bb = blockIdx.z;
    const int bh = bb * NHEADS + hh;
    const int q0 = qb * 64;
    const size_t kvbase = (size_t)bh * SEQ * HDIM;

    // stage Q (64 x 64 bf16)
    #pragma unroll
    for (int i = 0; i < 2; i++) {
        int idx = tid + 256 * i;
        int row = idx >> 3, ch = idx & 7;
        short8 v = *(const short8*)(Qb + kvbase + (size_t)(q0 + row) * HDIM + ch * 8);
        *(short8*)&Ql[row * 72 + ch * 8] = v;
    }
    __syncthreads();
    short8 qf[2];
    #pragma unroll
    for (int ks = 0; ks < 2; ks++)
        qf[ks] = *(const short8*)&Ql[(wv * 16 + l15) * 72 + ks * 32 + g * 8];

    float m[4], lsum[4];
    floatx4 of[4];
    #pragma unroll
    for (int r = 0; r < 4; r++) { m[r] = -__builtin_inff(); lsum[r] = 0.f; }
    #pragma unroll
    for (int fn = 0; fn < 4; fn++) of[fn] = floatx4{0.f, 0.f, 0.f, 0.f};

    const int nt = qb * 2 + 2;
    for (int tkv = 0; tkv < nt; tkv++) {
        const int kv0 = tkv * 32;
        {   // stage K tile (32 keys x 64 d)
            int key = tid >> 3, ch = tid & 7;
            short8 v = *(const short8*)(Kb + kvbase + (size_t)(kv0 + key) * HDIM + ch * 8);
            *(short8*)&Kl[key * 72 + ch * 8] = v;
        }
        {   // stage V tile transposed: Vt[d][key]
            int key = tid >> 3, ch = tid & 7;
            short8 v = *(const short8*)(Vb + kvbase + (size_t)(kv0 + key) * HDIM + ch * 8);
            #pragma unroll
            for (int r = 0; r < 8; r++)
                Vt[(ch * 8 + r) * 40 + key] = (ushort)v[r];
        }
        __syncthreads();

        // QK^T: S (16q x 32key) per wave
        floatx4 sf[2];
        #pragma unroll
        for (int fn = 0; fn < 2; fn++) {
            sf[fn] = floatx4{0.f, 0.f, 0.f, 0.f};
            #pragma unroll
            for (int ks = 0; ks < 2; ks++) {
                short8 kf = *(const short8*)&Kl[(fn * 16 + l15) * 72 + ks * 32 + g * 8];
                sf[fn] = mfma_bf16(qf[ks], kf, sf[fn]);
            }
        }
        // scale + causal mask + tile max
        float sv[2][4], tmax[4];
        #pragma unroll
        for (int r = 0; r < 4; r++) tmax[r] = -__builtin_inff();
        #pragma unroll
        for (int fn = 0; fn < 2; fn++) {
            int key = kv0 + fn * 16 + l15;
            #pragma unroll
            for (int r = 0; r < 4; r++) {
                int qrow = q0 + wv * 16 + g * 4 + r;
                float x = sf[fn][r] * 0.125f;
                if (key > qrow) x = -1e9f;
                sv[fn][r] = x;
                tmax[r] = fmaxf(tmax[r], x);
            }
        }
        #pragma unroll
        for (int r = 0; r < 4; r++) {
            tmax[r] = fmaxf(tmax[r], __shfl_xor(tmax[r], 1, 64));
            tmax[r] = fmaxf(tmax[r], __shfl_xor(tmax[r], 2, 64));
            tmax[r] = fmaxf(tmax[r], __shfl_xor(tmax[r], 4, 64));
            tmax[r] = fmaxf(tmax[r], __shfl_xor(tmax[r], 8, 64));
        }
        float f[4], rs[4];
        #pragma unroll
        for (int r = 0; r < 4; r++) {
            float mnew = fmaxf(m[r], tmax[r]);
            f[r] = __expf(m[r] - mnew);
            m[r] = mnew;
            rs[r] = 0.f;
        }
        // P = exp(S - m), store bf16 to per-wave LDS (D-layout -> A-layout transpose)
        #pragma unroll
        for (int fn = 0; fn < 2; fn++) {
            #pragma unroll
            for (int r = 0; r < 4; r++) {
                float p = __expf(sv[fn][r] - m[r]);
                rs[r] += p;
                Pl[wv * 640 + (g * 4 + r) * 40 + fn * 16 + l15] = f2bf(p);
            }
        }
        #pragma unroll
        for (int r = 0; r < 4; r++) {
            rs[r] += __shfl_xor(rs[r], 1, 64);
            rs[r] += __shfl_xor(rs[r], 2, 64);
            rs[r] += __shfl_xor(rs[r], 4, 64);
            rs[r] += __shfl_xor(rs[r], 8, 64);
            lsum[r] = lsum[r] * f[r] + rs[r];
        }
        // rescale O
        #pragma unroll
        for (int fn = 0; fn < 4; fn++)
            #pragma unroll
            for (int r = 0; r < 4; r++)
                of[fn][r] *= f[r];
        asm volatile("" ::: "memory");  // keep P writes before P read
        // PV: O += P @ V
        short8 pa = *(const short8*)&Pl[wv * 640 + l15 * 40 + g * 8];
        #pragma unroll
        for (int fn = 0; fn < 4; fn++) {
            short8 vf = *(const short8*)&Vt[(fn * 16 + l15) * 40 + g * 8];
            of[fn] = mfma_bf16(pa, vf, of[fn]);
        }
        __syncthreads();
    }

    // epilogue: O /= l, store attn (b, s, H) bf16
    #pragma unroll
    for (int fn = 0; fn < 4; fn++) {
        #pragma unroll
        for (int r = 0; r < 4; r++) {
            int qrow = q0 + wv * 16 + g * 4 + r;
            float o = of[fn][r] / lsum[r];
            attn[((size_t)bb * SEQ + qrow) * HID + hh * 64 + fn * 16 + l15] = f2bf(o);
        }
    }
}

// ---------------------------------------------------------------------------
// Kernel 3: out = attn @ w_out (M=4096, N=1024, K=1024), fp32 output
// ---------------------------------------------------------------------------
__global__ __launch_bounds__(256) void out_proj_kernel(
    const ushort* __restrict__ attn,   // (4096, 1024) bf16
    const float* __restrict__ wout,    // (1024, 1024)
    float* __restrict__ out)
{
    __shared__ ushort Al[128 * 40];
    __shared__ ushort Bl[128 * 40];
    const int tid  = threadIdx.x;
    const int lane = tid & 63;
    const int wv   = tid >> 6;
    const int g    = lane >> 4;
    const int l15  = lane & 15;
    const int m0 = blockIdx.y * 128;
    const int n0 = blockIdx.x * 128;
    const int wr = (wv >> 1) * 64;
    const int wc = (wv & 1) * 64;

    floatx4 acc[4][4];
    #pragma unroll
    for (int a = 0; a < 4; a++)
        #pragma unroll
        for (int bq = 0; bq < 4; bq++)
            acc[a][bq] = floatx4{0.f, 0.f, 0.f, 0.f};

    for (int k0 = 0; k0 < 1024; k0 += 32) {
        // stage A (already bf16): 128 rows x 32 k
        #pragma unroll
        for (int i = 0; i < 2; i++) {
            int idx = tid + 256 * i;
            int row = idx >> 2, ch = idx & 3;
            short8 v = *(const short8*)(attn + (size_t)(m0 + row) * 1024 + k0 + ch * 8);
            *(short8*)&Al[row * 40 + ch * 8] = v;
        }
        // stage B transposed (fp32 -> bf16)
        #pragma unroll
        for (int i = 0; i < 4; i++) {
            int idx = tid + 256 * i;
            int n = idx & 127, kq = idx >> 7;
            const float* src = wout + (size_t)(k0 + kq * 4) * 1024 + n0 + n;
            float a0 = src[0];
            float a1 = src[1024];
            float a2 = src[2048];
            float a3 = src[3072];
            uint2 u;
            u.x = (uint)f2bf(a0) | ((uint)f2bf(a1) << 16);
            u.y = (uint)f2bf(a2) | ((uint)f2bf(a3) << 16);
            *(uint2*)&Bl[n * 40 + kq * 4] = u;
        }
        __syncthreads();
        short8 af[4], bfr[4];
        #pragma unroll
        for (int fm = 0; fm < 4; fm++)
            af[fm] = *(const short8*)&Al[(wr + fm * 16 + l15) * 40 + g * 8];
        #pragma unroll
        for (int fn = 0; fn < 4; fn++)
            bfr[fn] = *(const short8*)&Bl[(wc + fn * 16 + l15) * 40 + g * 8];
        #pragma unroll
        for (int fm = 0; fm < 4; fm++)
            #pragma unroll
            for (int fn = 0; fn < 4; fn++)
                acc[fm][fn] = mfma_bf16(af[fm], bfr[fn], acc[fm][fn]);
        __syncthreads();
    }
    #pragma unroll
    for (int fm = 0; fm < 4; fm++)
        #pragma unroll
        for (int fn = 0; fn < 4; fn++)
            #pragma unroll
            for (int r = 0; r < 4; r++) {
                int row = m0 + wr + fm * 16 + g * 4 + r;
                int col = n0 + wc + fn * 16 + l15;
                out[(size_t)row * 1024 + col] = acc[fm][fn][r];
            }
}

// ---------------------------------------------------------------------------
extern "C" void kernel_launch(void* const* d_in, const int* in_sizes, int n_in,
                              void* d_out, int out_size, void* d_ws, size_t ws_size,
                              hipStream_t stream)
{
    const float* hidden = (const float*)d_in[0];
    const float* wqkv   = (const float*)d_in[1];
    const float* wout   = (const float*)d_in[2];
    float* out = (float*)d_out;

    const size_t NELEM = (size_t)2 * NHEADS * SEQ * HDIM;  // 4,194,304
    ushort* Qb   = (ushort*)d_ws;
    ushort* Kb   = Qb + NELEM;
    ushort* Vb   = Kb + NELEM;
    ushort* attn = Vb + NELEM;

    qkv_rope_kernel<<<dim3(24, 32), 256, 0, stream>>>(hidden, wqkv, Qb, Kb, Vb);
    attn_kernel<<<dim3(32, NHEADS, 2), 256, 0, stream>>>(Qb, Kb, Vb, attn);
    out_proj_kernel<<<dim3(8, 32), 256, 0, stream>>>(attn, wout, out);
}

// Round 2
// 222.700 us; speedup vs baseline: 1.5410x; 1.5410x over previous
//
#include <hip/hip_runtime.h>

#define SEQ   2048
#define NHEADS 16
#define HDIM  64
#define HID   1024
#define ROT   32

typedef __attribute__((ext_vector_type(8))) short  short8;
typedef __attribute__((ext_vector_type(4))) float  floatx4;

__device__ __forceinline__ ushort f2bf(float f) {
    union { float f; uint u; } v; v.f = f;
    uint x = v.u;
    uint r = (x + 0x7FFFu + ((x >> 16) & 1u)) >> 16;
    return (ushort)r;
}

__device__ __forceinline__ floatx4 mfma_bf16(short8 a, short8 b, floatx4 c) {
    return __builtin_amdgcn_mfma_f32_16x16x32_bf16(a, b, c, 0, 0, 0);
}

// ---------------------------------------------------------------------------
// Kernel 1: qkv = hidden @ w_qkv  (M=4096, N=3072, K=1024), fused RoPE +
// head split. Q,K written (b,h,s,d) bf16; V written (b,h,d,s) bf16 so the
// attention kernel can stage V^T with coalesced row loads.
// ---------------------------------------------------------------------------
__global__ __launch_bounds__(256) void qkv_rope_kernel(
    const float* __restrict__ hidden,   // (4096, 1024)
    const float* __restrict__ wqkv,     // (1024, 3072)
    ushort* __restrict__ Qb, ushort* __restrict__ Kb, ushort* __restrict__ Vb)
{
    __shared__ ushort Al[128 * 40];
    __shared__ ushort Bl[128 * 40];
    const int tid  = threadIdx.x;
    const int lane = tid & 63;
    const int wv   = tid >> 6;
    const int g    = lane >> 4;
    const int l15  = lane & 15;
    const int m0 = blockIdx.y * 128;
    const int n0 = blockIdx.x * 128;
    const int wr = (wv >> 1) * 64;
    const int wc = (wv & 1) * 64;

    floatx4 acc[4][4];
    #pragma unroll
    for (int a = 0; a < 4; a++)
        #pragma unroll
        for (int bq = 0; bq < 4; bq++)
            acc[a][bq] = floatx4{0.f, 0.f, 0.f, 0.f};

    for (int k0 = 0; k0 < 1024; k0 += 32) {
        #pragma unroll
        for (int i = 0; i < 4; i++) {
            int idx = tid + 256 * i;
            int row = idx >> 3;
            int kc  = (idx & 7) << 2;
            const float4 v = *(const float4*)(hidden + (size_t)(m0 + row) * 1024 + k0 + kc);
            uint2 u;
            u.x = (uint)f2bf(v.x) | ((uint)f2bf(v.y) << 16);
            u.y = (uint)f2bf(v.z) | ((uint)f2bf(v.w) << 16);
            *(uint2*)&Al[row * 40 + kc] = u;
        }
        #pragma unroll
        for (int i = 0; i < 4; i++) {
            int idx = tid + 256 * i;
            int n   = idx & 127;
            int kq  = idx >> 7;
            const float* src = wqkv + (size_t)(k0 + kq * 4) * 3072 + n0 + n;
            float a0 = src[0];
            float a1 = src[3072];
            float a2 = src[6144];
            float a3 = src[9216];
            uint2 u;
            u.x = (uint)f2bf(a0) | ((uint)f2bf(a1) << 16);
            u.y = (uint)f2bf(a2) | ((uint)f2bf(a3) << 16);
            *(uint2*)&Bl[n * 40 + kq * 4] = u;
        }
        __syncthreads();
        short8 af[4], bfr[4];
        #pragma unroll
        for (int fm = 0; fm < 4; fm++)
            af[fm] = *(const short8*)&Al[(wr + fm * 16 + l15) * 40 + g * 8];
        #pragma unroll
        for (int fn = 0; fn < 4; fn++)
            bfr[fn] = *(const short8*)&Bl[(wc + fn * 16 + l15) * 40 + g * 8];
        #pragma unroll
        for (int fm = 0; fm < 4; fm++)
            #pragma unroll
            for (int fn = 0; fn < 4; fn++)
                acc[fm][fn] = mfma_bf16(af[fm], bfr[fn], acc[fm][fn]);
        __syncthreads();
    }

    #pragma unroll
    for (int fn = 0; fn < 4; fn++) {
        const int c    = n0 + wc + fn * 16 + l15;
        const int mp   = c / 384;
        const int rem  = c - mp * 384;
        const int tsel = rem >> 7;                    // 0=q 1=k 2=v
        const int j    = (rem >> 6) & 1;
        const int d    = rem & 63;
        const int head = mp * 2 + j;
        ushort* basep = (tsel == 0) ? Qb : (tsel == 1) ? Kb : Vb;
        const bool rope = (tsel < 2) && (d < ROT);
        float freq = 0.f;
        if (rope) {
            freq = exp2f((float)(d >> 1) * -0.830482023721841f);
        }
        #pragma unroll
        for (int fm = 0; fm < 4; fm++) {
            #pragma unroll
            for (int r = 0; r < 4; r++) {
                int row = m0 + wr + fm * 16 + g * 4 + r;
                int bb  = row >> 11;
                int s   = row & 2047;
                float val = acc[fm][fn][r];
                float pv  = __shfl_xor(val, 1, 64);
                float outv = val;
                if (rope) {
                    float ang = (float)s * freq;
                    float sn, cs;
                    sincosf(ang, &sn, &cs);
                    outv = ((d & 1) == 0) ? (val * cs - pv * sn)
                                          : (val * cs + pv * sn);
                }
                size_t off;
                if (tsel == 2)
                    off = ((size_t)(bb * NHEADS + head) * HDIM + d) * SEQ + s;
                else
                    off = ((size_t)(bb * NHEADS + head) * SEQ + s) * HDIM + d;
                basep[off] = f2bf(outv);
            }
        }
    }
}

// ---------------------------------------------------------------------------
// Kernel 2: flash attention, causal. 1 WG = 128 q-rows of one (b,h),
// 4 waves x 32 q-rows, KV tiles of 64. Swapped QK^T (D[key][q]) keeps P
// lane-local for PV — no LDS P round-trip, no V scatter (V is (b,h,d,s)).
// ---------------------------------------------------------------------------
__global__ __launch_bounds__(256) void attn_kernel(
    const ushort* __restrict__ Qb, const ushort* __restrict__ Kb,
    const ushort* __restrict__ Vb, ushort* __restrict__ attn)
{
    __shared__ ushort Kl[64 * 72];      // [key][d], stride 72
    __shared__ ushort Vt[64 * 72];      // [d][key], stride 72

    const int tid  = threadIdx.x;
    const int lane = tid & 63;
    const int wv   = tid >> 6;
    const int g    = lane >> 4;
    const int l15  = lane & 15;
    const int qb = 15 - blockIdx.x;     // heavy blocks dispatch first
    const int hh = blockIdx.y, bb = blockIdx.z;
    const int q0 = qb * 128;
    const int wq = wv * 32;
    const size_t kvbase = (size_t)(bb * NHEADS + hh) * SEQ * HDIM;

    // Q fragments direct global->reg, hoisted for whole kernel.
    // B-frag pairing: element j of group g reads d = ks*32 + g*8 + j.
    short8 qreg[2][2];
    #pragma unroll
    for (int qf = 0; qf < 2; qf++)
        #pragma unroll
        for (int ks = 0; ks < 2; ks++)
            qreg[qf][ks] = *(const short8*)(Qb + kvbase +
                (size_t)(q0 + wq + qf * 16 + l15) * HDIM + ks * 32 + g * 8);

    float m[2], lsum[2];
    floatx4 of[2][4];
    #pragma unroll
    for (int qf = 0; qf < 2; qf++) { m[qf] = -__builtin_inff(); lsum[qf] = 0.f; }
    #pragma unroll
    for (int mf = 0; mf < 2; mf++)
        #pragma unroll
        for (int df = 0; df < 4; df++)
            of[mf][df] = floatx4{0.f, 0.f, 0.f, 0.f};

    const int nt = 2 * qb + 2;
    for (int t = 0; t < nt; t++) {
        const int kv0 = t * 64;
        // stage K: [key][d]
        #pragma unroll
        for (int i = 0; i < 2; i++) {
            int idx = tid + 256 * i;
            int row = idx >> 3, ch = idx & 7;
            *(short8*)&Kl[row * 72 + ch * 8] =
                *(const short8*)(Kb + kvbase + (size_t)(kv0 + row) * HDIM + ch * 8);
        }
        // stage V^T: [d][key] — V already stored (b,h,d,s), coalesced rows
        #pragma unroll
        for (int i = 0; i < 2; i++) {
            int idx = tid + 256 * i;
            int d = idx >> 3, ch = idx & 7;
            *(short8*)&Vt[d * 72 + ch * 8] =
                *(const short8*)(Vb + kvbase + (size_t)d * SEQ + kv0 + ch * 8);
        }
        __syncthreads();

        if (kv0 <= q0 + wq + 31) {   // skip fully-masked tiles (wave-uniform)
            // QK^T swapped: sf[kf][qf], D[key][q]: lane l15 = q, key = kf*16+g*4+r
            floatx4 sf[4][2];
            #pragma unroll
            for (int kf = 0; kf < 4; kf++) {
                short8 kr0 = *(const short8*)&Kl[(kf * 16 + l15) * 72 + g * 8];
                short8 kr1 = *(const short8*)&Kl[(kf * 16 + l15) * 72 + 32 + g * 8];
                #pragma unroll
                for (int qf = 0; qf < 2; qf++) {
                    floatx4 s = floatx4{0.f, 0.f, 0.f, 0.f};
                    s = mfma_bf16(kr0, qreg[qf][0], s);
                    s = mfma_bf16(kr1, qreg[qf][1], s);
                    sf[kf][qf] = s;
                }
            }
            // softmax (in-register, per-lane q = qf*16 + l15)
            float f[2];
            #pragma unroll
            for (int qf = 0; qf < 2; qf++) {
                const int qg = q0 + wq + qf * 16 + l15;
                float tmax = -__builtin_inff();
                #pragma unroll
                for (int kf = 0; kf < 4; kf++) {
                    #pragma unroll
                    for (int r = 0; r < 4; r++) {
                        int key = kv0 + kf * 16 + g * 4 + r;
                        float x = sf[kf][qf][r] * 0.125f;
                        if (key > qg) x = -1e9f;
                        sf[kf][qf][r] = x;
                        tmax = fmaxf(tmax, x);
                    }
                }
                tmax = fmaxf(tmax, __shfl_xor(tmax, 16, 64));
                tmax = fmaxf(tmax, __shfl_xor(tmax, 32, 64));
                float mnew = fmaxf(m[qf], tmax);
                f[qf] = __expf(m[qf] - mnew);
                m[qf] = mnew;
                float rs = 0.f;
                #pragma unroll
                for (int kf = 0; kf < 4; kf++) {
                    #pragma unroll
                    for (int r = 0; r < 4; r++) {
                        float p = __expf(sf[kf][qf][r] - mnew);
                        sf[kf][qf][r] = p;
                        rs += p;
                    }
                }
                rs += __shfl_xor(rs, 16, 64);
                rs += __shfl_xor(rs, 32, 64);
                lsum[qf] = lsum[qf] * f[qf] + rs;
            }
            // pack P into A-frags (lane-local): elem j = sf[2ks+(j>>2)][qf].r[j&3]
            short8 pa[2][2];
            #pragma unroll
            for (int qf = 0; qf < 2; qf++)
                #pragma unroll
                for (int ks = 0; ks < 2; ks++)
                    #pragma unroll
                    for (int j = 0; j < 8; j++)
                        pa[qf][ks][j] = (short)f2bf(sf[2 * ks + (j >> 2)][qf][j & 3]);
            // rescale O: O-row q = mf*16 + g*4 + r; f lives at lane l15 = g*4+r
            #pragma unroll
            for (int mf = 0; mf < 2; mf++) {
                #pragma unroll
                for (int r = 0; r < 4; r++) {
                    float fr = __shfl(f[mf], g * 4 + r, 64);
                    #pragma unroll
                    for (int df = 0; df < 4; df++)
                        of[mf][df][r] *= fr;
                }
            }
            // PV: B-frag elem j reads Vt[d][ks*32 + 16*(j>>2) + g*4 + (j&3)]
            #pragma unroll
            for (int df = 0; df < 4; df++) {
                #pragma unroll
                for (int ks = 0; ks < 2; ks++) {
                    const int vb = (df * 16 + l15) * 72 + ks * 32 + g * 4;
                    uint2 v0 = *(const uint2*)&Vt[vb];
                    uint2 v1 = *(const uint2*)&Vt[vb + 16];
                    union { short8 s; uint4 u; } vv;
                    vv.u.x = v0.x; vv.u.y = v0.y; vv.u.z = v1.x; vv.u.w = v1.y;
                    #pragma unroll
                    for (int mf = 0; mf < 2; mf++)
                        of[mf][df] = mfma_bf16(pa[mf][ks], vv.s, of[mf][df]);
                }
            }
        }
        __syncthreads();
    }

    // epilogue: O /= l, store attn (b, s, H) bf16
    #pragma unroll
    for (int mf = 0; mf < 2; mf++) {
        #pragma unroll
        for (int r = 0; r < 4; r++) {
            float lr = __shfl(lsum[mf], g * 4 + r, 64);
            float inv = 1.0f / lr;
            int q = q0 + wq + mf * 16 + g * 4 + r;
            #pragma unroll
            for (int df = 0; df < 4; df++)
                attn[((size_t)bb * SEQ + q) * HID + hh * 64 + df * 16 + l15] =
                    f2bf(of[mf][df][r] * inv);
        }
    }
}

// ---------------------------------------------------------------------------
// Kernel 3: out = attn @ w_out (M=4096, N=1024, K=1024), fp32 output
// ---------------------------------------------------------------------------
__global__ __launch_bounds__(256) void out_proj_kernel(
    const ushort* __restrict__ attn,   // (4096, 1024) bf16
    const float* __restrict__ wout,    // (1024, 1024)
    float* __restrict__ out)
{
    __shared__ ushort Al[128 * 40];
    __shared__ ushort Bl[128 * 40];
    const int tid  = threadIdx.x;
    const int lane = tid & 63;
    const int wv   = tid >> 6;
    const int g    = lane >> 4;
    const int l15  = lane & 15;
    const int m0 = blockIdx.y * 128;
    const int n0 = blockIdx.x * 128;
    const int wr = (wv >> 1) * 64;
    const int wc = (wv & 1) * 64;

    floatx4 acc[4][4];
    #pragma unroll
    for (int a = 0; a < 4; a++)
        #pragma unroll
        for (int bq = 0; bq < 4; bq++)
            acc[a][bq] = floatx4{0.f, 0.f, 0.f, 0.f};

    for (int k0 = 0; k0 < 1024; k0 += 32) {
        #pragma unroll
        for (int i = 0; i < 2; i++) {
            int idx = tid + 256 * i;
            int row = idx >> 2, ch = idx & 3;
            short8 v = *(const short8*)(attn + (size_t)(m0 + row) * 1024 + k0 + ch * 8);
            *(short8*)&Al[row * 40 + ch * 8] = v;
        }
        #pragma unroll
        for (int i = 0; i < 4; i++) {
            int idx = tid + 256 * i;
            int n = idx & 127, kq = idx >> 7;
            const float* src = wout + (size_t)(k0 + kq * 4) * 1024 + n0 + n;
            float a0 = src[0];
            float a1 = src[1024];
            float a2 = src[2048];
            float a3 = src[3072];
            uint2 u;
            u.x = (uint)f2bf(a0) | ((uint)f2bf(a1) << 16);
            u.y = (uint)f2bf(a2) | ((uint)f2bf(a3) << 16);
            *(uint2*)&Bl[n * 40 + kq * 4] = u;
        }
        __syncthreads();
        short8 af[4], bfr[4];
        #pragma unroll
        for (int fm = 0; fm < 4; fm++)
            af[fm] = *(const short8*)&Al[(wr + fm * 16 + l15) * 40 + g * 8];
        #pragma unroll
        for (int fn = 0; fn < 4; fn++)
            bfr[fn] = *(const short8*)&Bl[(wc + fn * 16 + l15) * 40 + g * 8];
        #pragma unroll
        for (int fm = 0; fm < 4; fm++)
            #pragma unroll
            for (int fn = 0; fn < 4; fn++)
                acc[fm][fn] = mfma_bf16(af[fm], bfr[fn], acc[fm][fn]);
        __syncthreads();
    }
    #pragma unroll
    for (int fm = 0; fm < 4; fm++)
        #pragma unroll
        for (int fn = 0; fn < 4; fn++)
            #pragma unroll
            for (int r = 0; r < 4; r++) {
                int row = m0 + wr + fm * 16 + g * 4 + r;
                int col = n0 + wc + fn * 16 + l15;
                out[(size_t)row * 1024 + col] = acc[fm][fn][r];
            }
}

// ---------------------------------------------------------------------------
extern "C" void kernel_launch(void* const* d_in, const int* in_sizes, int n_in,
                              void* d_out, int out_size, void* d_ws, size_t ws_size,
                              hipStream_t stream)
{
    const float* hidden = (const float*)d_in[0];
    const float* wqkv   = (const float*)d_in[1];
    const float* wout   = (const float*)d_in[2];
    float* out = (float*)d_out;

    const size_t NELEM = (size_t)2 * NHEADS * SEQ * HDIM;  // 4,194,304
    ushort* Qb   = (ushort*)d_ws;
    ushort* Kb   = Qb + NELEM;
    ushort* Vb   = Kb + NELEM;
    ushort* attn = Vb + NELEM;

    qkv_rope_kernel<<<dim3(24, 32), 256, 0, stream>>>(hidden, wqkv, Qb, Kb, Vb);
    attn_kernel<<<dim3(16, NHEADS, 2), 256, 0, stream>>>(Qb, Kb, Vb, attn);
    out_proj_kernel<<<dim3(8, 32), 256, 0, stream>>>(attn, wout, out);
}

// Round 3
// 195.167 us; speedup vs baseline: 1.7584x; 1.1411x over previous
//
#include <hip/hip_runtime.h>

#define SEQ   2048
#define NHEADS 16
#define HDIM  64
#define HID   1024
#define ROT   32

typedef __attribute__((ext_vector_type(8))) short  short8;
typedef __attribute__((ext_vector_type(4))) float  floatx4;

__device__ __forceinline__ ushort f2bf(float f) {
    union { float f; uint u; } v; v.f = f;
    uint x = v.u;
    uint r = (x + 0x7FFFu + ((x >> 16) & 1u)) >> 16;
    return (ushort)r;
}

__device__ __forceinline__ floatx4 mfma_bf16(short8 a, short8 b, floatx4 c) {
    return __builtin_amdgcn_mfma_f32_16x16x32_bf16(a, b, c, 0, 0, 0);
}

__device__ __forceinline__ void gload16(const ushort* g, ushort* l) {
    __builtin_amdgcn_global_load_lds(
        (const __attribute__((address_space(1))) void*)g,
        (__attribute__((address_space(3))) void*)l, 16, 0, 0);
}

// ---------------------------------------------------------------------------
// Pre-pass A: fp32 -> bf16 elementwise (hidden)
// ---------------------------------------------------------------------------
__global__ __launch_bounds__(256) void convert_bf16_kernel(
    const float* __restrict__ src, ushort* __restrict__ dst, int n)
{
    int i = (blockIdx.x * 256 + threadIdx.x) * 8;
    if (i >= n) return;
    float4 a = *(const float4*)(src + i);
    float4 b = *(const float4*)(src + i + 4);
    short8 v;
    v[0] = (short)f2bf(a.x); v[1] = (short)f2bf(a.y);
    v[2] = (short)f2bf(a.z); v[3] = (short)f2bf(a.w);
    v[4] = (short)f2bf(b.x); v[5] = (short)f2bf(b.y);
    v[6] = (short)f2bf(b.z); v[7] = (short)f2bf(b.w);
    *(short8*)(dst + i) = v;
}

// ---------------------------------------------------------------------------
// Pre-pass B: fp32 (K,N) -> bf16 (N,K) transpose-convert. Tile 64x64.
// ---------------------------------------------------------------------------
__global__ __launch_bounds__(256) void transpose_bf16_kernel(
    const float* __restrict__ src, ushort* __restrict__ dst, int K, int N)
{
    __shared__ ushort Tl[64 * 68];
    const int k0 = blockIdx.y * 64, n0 = blockIdx.x * 64;
    const int tid = threadIdx.x;
    #pragma unroll
    for (int i = 0; i < 4; i++) {
        int lin = tid + 256 * i;
        int row = lin >> 4;            // k
        int c4  = (lin & 15) * 4;      // n
        float4 v = *(const float4*)(src + (size_t)(k0 + row) * N + n0 + c4);
        uint2 u;
        u.x = (uint)f2bf(v.x) | ((uint)f2bf(v.y) << 16);
        u.y = (uint)f2bf(v.z) | ((uint)f2bf(v.w) << 16);
        *(uint2*)&Tl[row * 68 + c4] = u;
    }
    __syncthreads();
    #pragma unroll
    for (int j = 0; j < 2; j++) {
        int lin = tid + 256 * j;
        int n = lin >> 3, c = lin & 7;
        short8 v;
        #pragma unroll
        for (int u = 0; u < 8; u++) v[u] = (short)Tl[(c * 8 + u) * 68 + n];
        *(short8*)(dst + (size_t)(n0 + n) * K + k0 + c * 8) = v;
    }
}

// ---------------------------------------------------------------------------
// Kernel 1: qkv = hidden @ w_qkv (M=4096, N=3072, K=1024) bf16 inputs,
// m97 structure: 128^2 tile, BK=32, global_load_lds staging, linear LDS.
// Fused RoPE + head-split epilogue. Q,K (b,h,s,d); V (b,h,d,s).
// ---------------------------------------------------------------------------
__global__ __launch_bounds__(256) void qkv_rope_kernel(
    const ushort* __restrict__ hbf,     // (4096,1024) bf16
    const ushort* __restrict__ wqkvT,   // (3072,1024) bf16 (N,K)
    ushort* __restrict__ Qb, ushort* __restrict__ Kb, ushort* __restrict__ Vb)
{
    __shared__ ushort Al[128 * 32];
    __shared__ ushort Bl[128 * 32];
    const int tid  = threadIdx.x;
    const int lane = tid & 63;
    const int wv   = tid >> 6;
    const int g    = lane >> 4;
    const int l15  = lane & 15;
    const int m0 = blockIdx.y * 128;
    const int n0 = blockIdx.x * 128;
    const int wr = (wv >> 1) * 64;
    const int wc = (wv & 1) * 64;
    const int rowl = lane >> 2;        // 0..15
    const int kcol = (lane & 3) * 8;

    floatx4 acc[4][4];
    #pragma unroll
    for (int a = 0; a < 4; a++)
        #pragma unroll
        for (int bq = 0; bq < 4; bq++)
            acc[a][bq] = floatx4{0.f, 0.f, 0.f, 0.f};

    const ushort* ga = hbf   + (size_t)(m0 + wv * 32 + rowl) * 1024 + kcol;
    const ushort* gb = wqkvT + (size_t)(n0 + wv * 32 + rowl) * 1024 + kcol;
    ushort* lA = &Al[wv * 1024];
    ushort* lB = &Bl[wv * 1024];

    for (int k0 = 0; k0 < 1024; k0 += 32) {
        gload16(ga + k0,             lA);
        gload16(ga + k0 + 16 * 1024, lA + 512);
        gload16(gb + k0,             lB);
        gload16(gb + k0 + 16 * 1024, lB + 512);
        __syncthreads();
        short8 af[4], bfr[4];
        #pragma unroll
        for (int fm = 0; fm < 4; fm++)
            af[fm] = *(const short8*)&Al[(wr + fm * 16 + l15) * 32 + g * 8];
        #pragma unroll
        for (int fn = 0; fn < 4; fn++)
            bfr[fn] = *(const short8*)&Bl[(wc + fn * 16 + l15) * 32 + g * 8];
        #pragma unroll
        for (int fm = 0; fm < 4; fm++)
            #pragma unroll
            for (int fn = 0; fn < 4; fn++)
                acc[fm][fn] = mfma_bf16(af[fm], bfr[fn], acc[fm][fn]);
        __syncthreads();
    }

    #pragma unroll
    for (int fn = 0; fn < 4; fn++) {
        const int c    = n0 + wc + fn * 16 + l15;
        const int mp   = c / 384;
        const int rem  = c - mp * 384;
        const int tsel = rem >> 7;                    // 0=q 1=k 2=v
        const int j    = (rem >> 6) & 1;
        const int d    = rem & 63;
        const int head = mp * 2 + j;
        ushort* basep = (tsel == 0) ? Qb : (tsel == 1) ? Kb : Vb;
        const bool rope = (tsel < 2) && (d < ROT);
        float freq = 0.f;
        if (rope) {
            freq = exp2f((float)(d >> 1) * -0.830482023721841f);
        }
        #pragma unroll
        for (int fm = 0; fm < 4; fm++) {
            #pragma unroll
            for (int r = 0; r < 4; r++) {
                int row = m0 + wr + fm * 16 + g * 4 + r;
                int bb  = row >> 11;
                int s   = row & 2047;
                float val = acc[fm][fn][r];
                float pv  = __shfl_xor(val, 1, 64);
                float outv = val;
                if (rope) {
                    float ang = (float)s * freq;
                    float sn, cs;
                    sincosf(ang, &sn, &cs);
                    outv = ((d & 1) == 0) ? (val * cs - pv * sn)
                                          : (val * cs + pv * sn);
                }
                size_t off;
                if (tsel == 2)
                    off = ((size_t)(bb * NHEADS + head) * HDIM + d) * SEQ + s;
                else
                    off = ((size_t)(bb * NHEADS + head) * SEQ + s) * HDIM + d;
                basep[off] = f2bf(outv);
            }
        }
    }
}

// ---------------------------------------------------------------------------
// Kernel 2: flash attention, causal (unchanged from round 2).
// ---------------------------------------------------------------------------
__global__ __launch_bounds__(256) void attn_kernel(
    const ushort* __restrict__ Qb, const ushort* __restrict__ Kb,
    const ushort* __restrict__ Vb, ushort* __restrict__ attn)
{
    __shared__ ushort Kl[64 * 72];      // [key][d], stride 72
    __shared__ ushort Vt[64 * 72];      // [d][key], stride 72

    const int tid  = threadIdx.x;
    const int lane = tid & 63;
    const int wv   = tid >> 6;
    const int g    = lane >> 4;
    const int l15  = lane & 15;
    const int qb = 15 - blockIdx.x;
    const int hh = blockIdx.y, bb = blockIdx.z;
    const int q0 = qb * 128;
    const int wq = wv * 32;
    const size_t kvbase = (size_t)(bb * NHEADS + hh) * SEQ * HDIM;

    short8 qreg[2][2];
    #pragma unroll
    for (int qf = 0; qf < 2; qf++)
        #pragma unroll
        for (int ks = 0; ks < 2; ks++)
            qreg[qf][ks] = *(const short8*)(Qb + kvbase +
                (size_t)(q0 + wq + qf * 16 + l15) * HDIM + ks * 32 + g * 8);

    float m[2], lsum[2];
    floatx4 of[2][4];
    #pragma unroll
    for (int qf = 0; qf < 2; qf++) { m[qf] = -__builtin_inff(); lsum[qf] = 0.f; }
    #pragma unroll
    for (int mf = 0; mf < 2; mf++)
        #pragma unroll
        for (int df = 0; df < 4; df++)
            of[mf][df] = floatx4{0.f, 0.f, 0.f, 0.f};

    const int nt = 2 * qb + 2;
    for (int t = 0; t < nt; t++) {
        const int kv0 = t * 64;
        #pragma unroll
        for (int i = 0; i < 2; i++) {
            int idx = tid + 256 * i;
            int row = idx >> 3, ch = idx & 7;
            *(short8*)&Kl[row * 72 + ch * 8] =
                *(const short8*)(Kb + kvbase + (size_t)(kv0 + row) * HDIM + ch * 8);
        }
        #pragma unroll
        for (int i = 0; i < 2; i++) {
            int idx = tid + 256 * i;
            int d = idx >> 3, ch = idx & 7;
            *(short8*)&Vt[d * 72 + ch * 8] =
                *(const short8*)(Vb + kvbase + (size_t)d * SEQ + kv0 + ch * 8);
        }
        __syncthreads();

        if (kv0 <= q0 + wq + 31) {
            floatx4 sf[4][2];
            #pragma unroll
            for (int kf = 0; kf < 4; kf++) {
                short8 kr0 = *(const short8*)&Kl[(kf * 16 + l15) * 72 + g * 8];
                short8 kr1 = *(const short8*)&Kl[(kf * 16 + l15) * 72 + 32 + g * 8];
                #pragma unroll
                for (int qf = 0; qf < 2; qf++) {
                    floatx4 s = floatx4{0.f, 0.f, 0.f, 0.f};
                    s = mfma_bf16(kr0, qreg[qf][0], s);
                    s = mfma_bf16(kr1, qreg[qf][1], s);
                    sf[kf][qf] = s;
                }
            }
            float f[2];
            #pragma unroll
            for (int qf = 0; qf < 2; qf++) {
                const int qg = q0 + wq + qf * 16 + l15;
                float tmax = -__builtin_inff();
                #pragma unroll
                for (int kf = 0; kf < 4; kf++) {
                    #pragma unroll
                    for (int r = 0; r < 4; r++) {
                        int key = kv0 + kf * 16 + g * 4 + r;
                        float x = sf[kf][qf][r] * 0.125f;
                        if (key > qg) x = -1e9f;
                        sf[kf][qf][r] = x;
                        tmax = fmaxf(tmax, x);
                    }
                }
                tmax = fmaxf(tmax, __shfl_xor(tmax, 16, 64));
                tmax = fmaxf(tmax, __shfl_xor(tmax, 32, 64));
                float mnew = fmaxf(m[qf], tmax);
                f[qf] = __expf(m[qf] - mnew);
                m[qf] = mnew;
                float rs = 0.f;
                #pragma unroll
                for (int kf = 0; kf < 4; kf++) {
                    #pragma unroll
                    for (int r = 0; r < 4; r++) {
                        float p = __expf(sf[kf][qf][r] - mnew);
                        sf[kf][qf][r] = p;
                        rs += p;
                    }
                }
                rs += __shfl_xor(rs, 16, 64);
                rs += __shfl_xor(rs, 32, 64);
                lsum[qf] = lsum[qf] * f[qf] + rs;
            }
            short8 pa[2][2];
            #pragma unroll
            for (int qf = 0; qf < 2; qf++)
                #pragma unroll
                for (int ks = 0; ks < 2; ks++)
                    #pragma unroll
                    for (int j = 0; j < 8; j++)
                        pa[qf][ks][j] = (short)f2bf(sf[2 * ks + (j >> 2)][qf][j & 3]);
            #pragma unroll
            for (int mf = 0; mf < 2; mf++) {
                #pragma unroll
                for (int r = 0; r < 4; r++) {
                    float fr = __shfl(f[mf], g * 4 + r, 64);
                    #pragma unroll
                    for (int df = 0; df < 4; df++)
                        of[mf][df][r] *= fr;
                }
            }
            #pragma unroll
            for (int df = 0; df < 4; df++) {
                #pragma unroll
                for (int ks = 0; ks < 2; ks++) {
                    const int vb = (df * 16 + l15) * 72 + ks * 32 + g * 4;
                    uint2 v0 = *(const uint2*)&Vt[vb];
                    uint2 v1 = *(const uint2*)&Vt[vb + 16];
                    union { short8 s; uint4 u; } vv;
                    vv.u.x = v0.x; vv.u.y = v0.y; vv.u.z = v1.x; vv.u.w = v1.y;
                    #pragma unroll
                    for (int mf = 0; mf < 2; mf++)
                        of[mf][df] = mfma_bf16(pa[mf][ks], vv.s, of[mf][df]);
                }
            }
        }
        __syncthreads();
    }

    #pragma unroll
    for (int mf = 0; mf < 2; mf++) {
        #pragma unroll
        for (int r = 0; r < 4; r++) {
            float lr = __shfl(lsum[mf], g * 4 + r, 64);
            float inv = 1.0f / lr;
            int q = q0 + wq + mf * 16 + g * 4 + r;
            #pragma unroll
            for (int df = 0; df < 4; df++)
                attn[((size_t)bb * SEQ + q) * HID + hh * 64 + df * 16 + l15] =
                    f2bf(of[mf][df][r] * inv);
        }
    }
}

// ---------------------------------------------------------------------------
// Kernel 3: out = attn @ w_out (M=4096, N=1024, K=1024), m97 structure,
// fp32 output.
// ---------------------------------------------------------------------------
__global__ __launch_bounds__(256) void out_proj_kernel(
    const ushort* __restrict__ attn,    // (4096,1024) bf16
    const ushort* __restrict__ woutT,   // (1024,1024) bf16 (N,K)
    float* __restrict__ out)
{
    __shared__ ushort Al[128 * 32];
    __shared__ ushort Bl[128 * 32];
    const int tid  = threadIdx.x;
    const int lane = tid & 63;
    const int wv   = tid >> 6;
    const int g    = lane >> 4;
    const int l15  = lane & 15;
    const int m0 = blockIdx.y * 128;
    const int n0 = blockIdx.x * 128;
    const int wr = (wv >> 1) * 64;
    const int wc = (wv & 1) * 64;
    const int rowl = lane >> 2;
    const int kcol = (lane & 3) * 8;

    floatx4 acc[4][4];
    #pragma unroll
    for (int a = 0; a < 4; a++)
        #pragma unroll
        for (int bq = 0; bq < 4; bq++)
            acc[a][bq] = floatx4{0.f, 0.f, 0.f, 0.f};

    const ushort* ga = attn  + (size_t)(m0 + wv * 32 + rowl) * 1024 + kcol;
    const ushort* gb = woutT + (size_t)(n0 + wv * 32 + rowl) * 1024 + kcol;
    ushort* lA = &Al[wv * 1024];
    ushort* lB = &Bl[wv * 1024];

    for (int k0 = 0; k0 < 1024; k0 += 32) {
        gload16(ga + k0,             lA);
        gload16(ga + k0 + 16 * 1024, lA + 512);
        gload16(gb + k0,             lB);
        gload16(gb + k0 + 16 * 1024, lB + 512);
        __syncthreads();
        short8 af[4], bfr[4];
        #pragma unroll
        for (int fm = 0; fm < 4; fm++)
            af[fm] = *(const short8*)&Al[(wr + fm * 16 + l15) * 32 + g * 8];
        #pragma unroll
        for (int fn = 0; fn < 4; fn++)
            bfr[fn] = *(const short8*)&Bl[(wc + fn * 16 + l15) * 32 + g * 8];
        #pragma unroll
        for (int fm = 0; fm < 4; fm++)
            #pragma unroll
            for (int fn = 0; fn < 4; fn++)
                acc[fm][fn] = mfma_bf16(af[fm], bfr[fn], acc[fm][fn]);
        __syncthreads();
    }
    #pragma unroll
    for (int fm = 0; fm < 4; fm++)
        #pragma unroll
        for (int fn = 0; fn < 4; fn++)
            #pragma unroll
            for (int r = 0; r < 4; r++) {
                int row = m0 + wr + fm * 16 + g * 4 + r;
                int col = n0 + wc + fn * 16 + l15;
                out[(size_t)row * 1024 + col] = acc[fm][fn][r];
            }
}

// ---------------------------------------------------------------------------
extern "C" void kernel_launch(void* const* d_in, const int* in_sizes, int n_in,
                              void* d_out, int out_size, void* d_ws, size_t ws_size,
                              hipStream_t stream)
{
    const float* hidden = (const float*)d_in[0];
    const float* wqkv   = (const float*)d_in[1];
    const float* wout   = (const float*)d_in[2];
    float* out = (float*)d_out;

    const size_t NELEM = (size_t)2 * SEQ * HID;   // 4,194,304
    ushort* Qb    = (ushort*)d_ws;
    ushort* Kb    = Qb + NELEM;
    ushort* Vb    = Kb + NELEM;
    ushort* hbf   = Vb + NELEM;                   // hidden bf16; later reused as attn
    ushort* wqkvT = hbf + NELEM;                  // 3072*1024
    ushort* woutT = wqkvT + (size_t)3072 * 1024;  // 1024*1024
    ushort* attnb = hbf;                          // alias: lifetime disjoint

    convert_bf16_kernel<<<2048, 256, 0, stream>>>(hidden, hbf, (int)NELEM);
    transpose_bf16_kernel<<<dim3(48, 16), 256, 0, stream>>>(wqkv, wqkvT, 1024, 3072);
    transpose_bf16_kernel<<<dim3(16, 16), 256, 0, stream>>>(wout, woutT, 1024, 1024);
    qkv_rope_kernel<<<dim3(24, 32), 256, 0, stream>>>(hbf, wqkvT, Qb, Kb, Vb);
    attn_kernel<<<dim3(16, NHEADS, 2), 256, 0, stream>>>(Qb, Kb, Vb, attnb);
    out_proj_kernel<<<dim3(8, 32), 256, 0, stream>>>(attnb, woutT, out);
}

// Round 4
// 185.061 us; speedup vs baseline: 1.8545x; 1.0546x over previous
//
#include <hip/hip_runtime.h>

#define SEQ   2048
#define NHEADS 16
#define HDIM  64
#define HID   1024
#define ROT   32

typedef __attribute__((ext_vector_type(8))) short  short8;
typedef __attribute__((ext_vector_type(4))) float  floatx4;

__device__ __forceinline__ ushort f2bf(float f) {
    union { float f; uint u; } v; v.f = f;
    uint x = v.u;
    uint r = (x + 0x7FFFu + ((x >> 16) & 1u)) >> 16;
    return (ushort)r;
}

__device__ __forceinline__ floatx4 mfma_bf16(short8 a, short8 b, floatx4 c) {
    return __builtin_amdgcn_mfma_f32_16x16x32_bf16(a, b, c, 0, 0, 0);
}

__device__ __forceinline__ void gload16(const ushort* g, ushort* l) {
    __builtin_amdgcn_global_load_lds(
        (const __attribute__((address_space(1))) void*)g,
        (__attribute__((address_space(3))) void*)l, 16, 0, 0);
}

// ---------------------------------------------------------------------------
// Pre-pass A: fp32 -> bf16 elementwise (hidden)
// ---------------------------------------------------------------------------
__global__ __launch_bounds__(256) void convert_bf16_kernel(
    const float* __restrict__ src, ushort* __restrict__ dst, int n)
{
    int i = (blockIdx.x * 256 + threadIdx.x) * 8;
    if (i >= n) return;
    float4 a = *(const float4*)(src + i);
    float4 b = *(const float4*)(src + i + 4);
    short8 v;
    v[0] = (short)f2bf(a.x); v[1] = (short)f2bf(a.y);
    v[2] = (short)f2bf(a.z); v[3] = (short)f2bf(a.w);
    v[4] = (short)f2bf(b.x); v[5] = (short)f2bf(b.y);
    v[6] = (short)f2bf(b.z); v[7] = (short)f2bf(b.w);
    *(short8*)(dst + i) = v;
}

// ---------------------------------------------------------------------------
// Pre-pass B: fp32 (K,N) -> bf16 (N,K) transpose-convert. Tile 64x64.
// ---------------------------------------------------------------------------
__global__ __launch_bounds__(256) void transpose_bf16_kernel(
    const float* __restrict__ src, ushort* __restrict__ dst, int K, int N)
{
    __shared__ ushort Tl[64 * 68];
    const int k0 = blockIdx.y * 64, n0 = blockIdx.x * 64;
    const int tid = threadIdx.x;
    #pragma unroll
    for (int i = 0; i < 4; i++) {
        int lin = tid + 256 * i;
        int row = lin >> 4;
        int c4  = (lin & 15) * 4;
        float4 v = *(const float4*)(src + (size_t)(k0 + row) * N + n0 + c4);
        uint2 u;
        u.x = (uint)f2bf(v.x) | ((uint)f2bf(v.y) << 16);
        u.y = (uint)f2bf(v.z) | ((uint)f2bf(v.w) << 16);
        *(uint2*)&Tl[row * 68 + c4] = u;
    }
    __syncthreads();
    #pragma unroll
    for (int j = 0; j < 2; j++) {
        int lin = tid + 256 * j;
        int n = lin >> 3, c = lin & 7;
        short8 v;
        #pragma unroll
        for (int u = 0; u < 8; u++) v[u] = (short)Tl[(c * 8 + u) * 68 + n];
        *(short8*)(dst + (size_t)(n0 + n) * K + k0 + c * 8) = v;
    }
}

// ---------------------------------------------------------------------------
// Kernel 1: qkv = hidden @ w_qkv (M=4096, N=3072, K=1024) bf16 inputs,
// m97 structure. Fused RoPE + head-split epilogue. Q is pre-scaled by
// 1/sqrt(HDIM) = 0.125 here (exact pow2, commutes with RoPE rotation).
// Q,K (b,h,s,d); V (b,h,d,s).
// ---------------------------------------------------------------------------
__global__ __launch_bounds__(256) void qkv_rope_kernel(
    const ushort* __restrict__ hbf,     // (4096,1024) bf16
    const ushort* __restrict__ wqkvT,   // (3072,1024) bf16 (N,K)
    ushort* __restrict__ Qb, ushort* __restrict__ Kb, ushort* __restrict__ Vb)
{
    __shared__ ushort Al[128 * 32];
    __shared__ ushort Bl[128 * 32];
    const int tid  = threadIdx.x;
    const int lane = tid & 63;
    const int wv   = tid >> 6;
    const int g    = lane >> 4;
    const int l15  = lane & 15;
    const int m0 = blockIdx.y * 128;
    const int n0 = blockIdx.x * 128;
    const int wr = (wv >> 1) * 64;
    const int wc = (wv & 1) * 64;
    const int rowl = lane >> 2;
    const int kcol = (lane & 3) * 8;

    floatx4 acc[4][4];
    #pragma unroll
    for (int a = 0; a < 4; a++)
        #pragma unroll
        for (int bq = 0; bq < 4; bq++)
            acc[a][bq] = floatx4{0.f, 0.f, 0.f, 0.f};

    const ushort* ga = hbf   + (size_t)(m0 + wv * 32 + rowl) * 1024 + kcol;
    const ushort* gb = wqkvT + (size_t)(n0 + wv * 32 + rowl) * 1024 + kcol;
    ushort* lA = &Al[wv * 1024];
    ushort* lB = &Bl[wv * 1024];

    for (int k0 = 0; k0 < 1024; k0 += 32) {
        gload16(ga + k0,             lA);
        gload16(ga + k0 + 16 * 1024, lA + 512);
        gload16(gb + k0,             lB);
        gload16(gb + k0 + 16 * 1024, lB + 512);
        __syncthreads();
        short8 af[4], bfr[4];
        #pragma unroll
        for (int fm = 0; fm < 4; fm++)
            af[fm] = *(const short8*)&Al[(wr + fm * 16 + l15) * 32 + g * 8];
        #pragma unroll
        for (int fn = 0; fn < 4; fn++)
            bfr[fn] = *(const short8*)&Bl[(wc + fn * 16 + l15) * 32 + g * 8];
        #pragma unroll
        for (int fm = 0; fm < 4; fm++)
            #pragma unroll
            for (int fn = 0; fn < 4; fn++)
                acc[fm][fn] = mfma_bf16(af[fm], bfr[fn], acc[fm][fn]);
        __syncthreads();
    }

    #pragma unroll
    for (int fn = 0; fn < 4; fn++) {
        const int c    = n0 + wc + fn * 16 + l15;
        const int mp   = c / 384;
        const int rem  = c - mp * 384;
        const int tsel = rem >> 7;                    // 0=q 1=k 2=v
        const int j    = (rem >> 6) & 1;
        const int d    = rem & 63;
        const int head = mp * 2 + j;
        ushort* basep = (tsel == 0) ? Qb : (tsel == 1) ? Kb : Vb;
        const bool rope = (tsel < 2) && (d < ROT);
        const float qscale = (tsel == 0) ? 0.125f : 1.0f;
        float freq = 0.f;
        if (rope) {
            freq = exp2f((float)(d >> 1) * -0.830482023721841f);
        }
        #pragma unroll
        for (int fm = 0; fm < 4; fm++) {
            #pragma unroll
            for (int r = 0; r < 4; r++) {
                int row = m0 + wr + fm * 16 + g * 4 + r;
                int bb  = row >> 11;
                int s   = row & 2047;
                float val = acc[fm][fn][r];
                float pv  = __shfl_xor(val, 1, 64);
                float outv = val;
                if (rope) {
                    float ang = (float)s * freq;
                    float sn, cs;
                    sincosf(ang, &sn, &cs);
                    outv = ((d & 1) == 0) ? (val * cs - pv * sn)
                                          : (val * cs + pv * sn);
                }
                outv *= qscale;
                size_t off;
                if (tsel == 2)
                    off = ((size_t)(bb * NHEADS + head) * HDIM + d) * SEQ + s;
                else
                    off = ((size_t)(bb * NHEADS + head) * SEQ + s) * HDIM + d;
                basep[off] = f2bf(outv);
            }
        }
    }
}

// ---------------------------------------------------------------------------
// Kernel 2: flash attention, causal. 128 q-rows/WG, 4 waves, KV tiles 64.
// Double-buffered LDS + async reg staging (T14), defer-max (T13),
// cvt_pk P-pack (T12), setprio around MFMA (T5). Q pre-scaled by 0.125.
// ---------------------------------------------------------------------------
__global__ __launch_bounds__(256) void attn_kernel(
    const ushort* __restrict__ Qb, const ushort* __restrict__ Kb,
    const ushort* __restrict__ Vb, ushort* __restrict__ attn)
{
    __shared__ ushort Kl[2][64 * 72];      // [key][d], stride 72
    __shared__ ushort Vt[2][64 * 72];      // [d][key], stride 72

    const int tid  = threadIdx.x;
    const int lane = tid & 63;
    const int wv   = tid >> 6;
    const int g    = lane >> 4;
    const int l15  = lane & 15;
    const int qb = 15 - blockIdx.x;        // heavy blocks first (LPT)
    const int hh = blockIdx.y, bb = blockIdx.z;
    const int q0 = qb * 128;
    const int wq = wv * 32;
    const size_t kvbase = (size_t)(bb * NHEADS + hh) * SEQ * HDIM;

    const int srow = tid >> 3;             // 0..31 staging row (plus +32)
    const int sch  = (tid & 7) * 8;        // staging col (ushort)

    short8 qreg[2][2];
    #pragma unroll
    for (int qf = 0; qf < 2; qf++)
        #pragma unroll
        for (int ks = 0; ks < 2; ks++)
            qreg[qf][ks] = *(const short8*)(Qb + kvbase +
                (size_t)(q0 + wq + qf * 16 + l15) * HDIM + ks * 32 + g * 8);

    float m[2], lsum[2];
    floatx4 of[2][4];
    #pragma unroll
    for (int qf = 0; qf < 2; qf++) { m[qf] = -__builtin_inff(); lsum[qf] = 0.f; }
    #pragma unroll
    for (int mf = 0; mf < 2; mf++)
        #pragma unroll
        for (int df = 0; df < 4; df++)
            of[mf][df] = floatx4{0.f, 0.f, 0.f, 0.f};

    const int nt = 2 * qb + 2;
    short8 kreg[2], vreg[2];

    // prologue: stage tile 0 into buf 0
    #pragma unroll
    for (int i = 0; i < 2; i++) {
        kreg[i] = *(const short8*)(Kb + kvbase + (size_t)(srow + 32 * i) * HDIM + sch);
        vreg[i] = *(const short8*)(Vb + kvbase + (size_t)(srow + 32 * i) * SEQ + sch);
    }
    #pragma unroll
    for (int i = 0; i < 2; i++) {
        *(short8*)&Kl[0][(srow + 32 * i) * 72 + sch] = kreg[i];
        *(short8*)&Vt[0][(srow + 32 * i) * 72 + sch] = vreg[i];
    }
    __syncthreads();

    for (int t = 0; t < nt; t++) {
        const int kv0 = t * 64;
        const int cur = t & 1;
        const bool pre = (t + 1 < nt);
        // issue next tile's global loads early (latency hides under compute)
        if (pre) {
            const int nkv0 = kv0 + 64;
            #pragma unroll
            for (int i = 0; i < 2; i++) {
                kreg[i] = *(const short8*)(Kb + kvbase + (size_t)(nkv0 + srow + 32 * i) * HDIM + sch);
                vreg[i] = *(const short8*)(Vb + kvbase + (size_t)(srow + 32 * i) * SEQ + nkv0 + sch);
            }
        }

        if (kv0 <= q0 + wq + 31) {
            const ushort* Kc = Kl[cur];
            const ushort* Vc = Vt[cur];
            // QK^T (swapped): sf[kf][qf], lane l15 = q, key = kf*16 + g*4 + r
            floatx4 sf[4][2];
            __builtin_amdgcn_s_setprio(1);
            #pragma unroll
            for (int kf = 0; kf < 4; kf++) {
                short8 kr0 = *(const short8*)&Kc[(kf * 16 + l15) * 72 + g * 8];
                short8 kr1 = *(const short8*)&Kc[(kf * 16 + l15) * 72 + 32 + g * 8];
                #pragma unroll
                for (int qf = 0; qf < 2; qf++) {
                    floatx4 s = floatx4{0.f, 0.f, 0.f, 0.f};
                    s = mfma_bf16(kr0, qreg[qf][0], s);
                    s = mfma_bf16(kr1, qreg[qf][1], s);
                    sf[kf][qf] = s;
                }
            }
            __builtin_amdgcn_s_setprio(0);

            const bool diag = (kv0 + 63 > q0 + wq);   // wave-uniform
            float f[2];
            int resc[2];
            #pragma unroll
            for (int qf = 0; qf < 2; qf++) {
                const int qg = q0 + wq + qf * 16 + l15;
                float tmax = -__builtin_inff();
                if (diag) {
                    #pragma unroll
                    for (int kf = 0; kf < 4; kf++) {
                        #pragma unroll
                        for (int r = 0; r < 4; r++) {
                            int key = kv0 + kf * 16 + g * 4 + r;
                            float x = sf[kf][qf][r];
                            if (key > qg) x = -1e9f;
                            sf[kf][qf][r] = x;
                            tmax = fmaxf(tmax, x);
                        }
                    }
                } else {
                    #pragma unroll
                    for (int kf = 0; kf < 4; kf++)
                        #pragma unroll
                        for (int r = 0; r < 4; r++)
                            tmax = fmaxf(tmax, sf[kf][qf][r]);
                }
                tmax = fmaxf(tmax, __shfl_xor(tmax, 16, 64));
                tmax = fmaxf(tmax, __shfl_xor(tmax, 32, 64));
                // defer-max: skip rescale unless max grew past threshold
                resc[qf] = !__all(tmax <= m[qf] + 8.0f);
                float mn = m[qf];
                if (resc[qf]) {
                    mn = fmaxf(m[qf], tmax);
                    f[qf] = __expf(m[qf] - mn);
                    m[qf] = mn;
                } else {
                    f[qf] = 1.0f;
                }
                float rs = 0.f;
                #pragma unroll
                for (int kf = 0; kf < 4; kf++) {
                    #pragma unroll
                    for (int r = 0; r < 4; r++) {
                        float p = __expf(sf[kf][qf][r] - mn);
                        sf[kf][qf][r] = p;
                        rs += p;
                    }
                }
                rs += __shfl_xor(rs, 16, 64);
                rs += __shfl_xor(rs, 32, 64);
                lsum[qf] = lsum[qf] * f[qf] + rs;
            }
            // pack P into lane-local A-frags via v_cvt_pk_bf16_f32
            short8 pa[2][2];
            #pragma unroll
            for (int qf = 0; qf < 2; qf++) {
                #pragma unroll
                for (int ks = 0; ks < 2; ks++) {
                    union { short8 s; uint u[4]; } pu;
                    #pragma unroll
                    for (int w = 0; w < 4; w++) {
                        const int kf = 2 * ks + (w >> 1);
                        float lo = sf[kf][qf][(w & 1) * 2 + 0];
                        float hi = sf[kf][qf][(w & 1) * 2 + 1];
                        asm("v_cvt_pk_bf16_f32 %0, %1, %2"
                            : "=v"(pu.u[w]) : "v"(lo), "v"(hi));
                    }
                    pa[qf][ks] = pu.s;
                }
            }
            // O rescale (only when some row's max actually grew)
            if (resc[0] | resc[1]) {
                #pragma unroll
                for (int mf = 0; mf < 2; mf++) {
                    if (resc[mf]) {
                        #pragma unroll
                        for (int r = 0; r < 4; r++) {
                            float fr = __shfl(f[mf], g * 4 + r, 64);
                            #pragma unroll
                            for (int df = 0; df < 4; df++)
                                of[mf][df][r] *= fr;
                        }
                    }
                }
            }
            // PV
            __builtin_amdgcn_s_setprio(1);
            #pragma unroll
            for (int df = 0; df < 4; df++) {
                #pragma unroll
                for (int ks = 0; ks < 2; ks++) {
                    const int vb = (df * 16 + l15) * 72 + ks * 32 + g * 4;
                    uint2 v0 = *(const uint2*)&Vc[vb];
                    uint2 v1 = *(const uint2*)&Vc[vb + 16];
                    union { short8 s; uint4 u; } vv;
                    vv.u.x = v0.x; vv.u.y = v0.y; vv.u.z = v1.x; vv.u.w = v1.y;
                    #pragma unroll
                    for (int mf = 0; mf < 2; mf++)
                        of[mf][df] = mfma_bf16(pa[mf][ks], vv.s, of[mf][df]);
                }
            }
            __builtin_amdgcn_s_setprio(0);
        }

        // write next tile into the other buffer (prev reads done: barrier t-1)
        if (pre) {
            const int nxt = cur ^ 1;
            #pragma unroll
            for (int i = 0; i < 2; i++) {
                *(short8*)&Kl[nxt][(srow + 32 * i) * 72 + sch] = kreg[i];
                *(short8*)&Vt[nxt][(srow + 32 * i) * 72 + sch] = vreg[i];
            }
        }
        __syncthreads();
    }

    // epilogue: O /= l, store attn (b, s, H) bf16
    #pragma unroll
    for (int mf = 0; mf < 2; mf++) {
        #pragma unroll
        for (int r = 0; r < 4; r++) {
            float lr = __shfl(lsum[mf], g * 4 + r, 64);
            float inv = 1.0f / lr;
            int q = q0 + wq + mf * 16 + g * 4 + r;
            #pragma unroll
            for (int df = 0; df < 4; df++)
                attn[((size_t)bb * SEQ + q) * HID + hh * 64 + df * 16 + l15] =
                    f2bf(of[mf][df][r] * inv);
        }
    }
}

// ---------------------------------------------------------------------------
// Kernel 3: out = attn @ w_out (M=4096, N=1024, K=1024), m97 structure.
// ---------------------------------------------------------------------------
__global__ __launch_bounds__(256) void out_proj_kernel(
    const ushort* __restrict__ attn,    // (4096,1024) bf16
    const ushort* __restrict__ woutT,   // (1024,1024) bf16 (N,K)
    float* __restrict__ out)
{
    __shared__ ushort Al[128 * 32];
    __shared__ ushort Bl[128 * 32];
    const int tid  = threadIdx.x;
    const int lane = tid & 63;
    const int wv   = tid >> 6;
    const int g    = lane >> 4;
    const int l15  = lane & 15;
    const int m0 = blockIdx.y * 128;
    const int n0 = blockIdx.x * 128;
    const int wr = (wv >> 1) * 64;
    const int wc = (wv & 1) * 64;
    const int rowl = lane >> 2;
    const int kcol = (lane & 3) * 8;

    floatx4 acc[4][4];
    #pragma unroll
    for (int a = 0; a < 4; a++)
        #pragma unroll
        for (int bq = 0; bq < 4; bq++)
            acc[a][bq] = floatx4{0.f, 0.f, 0.f, 0.f};

    const ushort* ga = attn  + (size_t)(m0 + wv * 32 + rowl) * 1024 + kcol;
    const ushort* gb = woutT + (size_t)(n0 + wv * 32 + rowl) * 1024 + kcol;
    ushort* lA = &Al[wv * 1024];
    ushort* lB = &Bl[wv * 1024];

    for (int k0 = 0; k0 < 1024; k0 += 32) {
        gload16(ga + k0,             lA);
        gload16(ga + k0 + 16 * 1024, lA + 512);
        gload16(gb + k0,             lB);
        gload16(gb + k0 + 16 * 1024, lB + 512);
        __syncthreads();
        short8 af[4], bfr[4];
        #pragma unroll
        for (int fm = 0; fm < 4; fm++)
            af[fm] = *(const short8*)&Al[(wr + fm * 16 + l15) * 32 + g * 8];
        #pragma unroll
        for (int fn = 0; fn < 4; fn++)
            bfr[fn] = *(const short8*)&Bl[(wc + fn * 16 + l15) * 32 + g * 8];
        #pragma unroll
        for (int fm = 0; fm < 4; fm++)
            #pragma unroll
            for (int fn = 0; fn < 4; fn++)
                acc[fm][fn] = mfma_bf16(af[fm], bfr[fn], acc[fm][fn]);
        __syncthreads();
    }
    #pragma unroll
    for (int fm = 0; fm < 4; fm++)
        #pragma unroll
        for (int fn = 0; fn < 4; fn++)
            #pragma unroll
            for (int r = 0; r < 4; r++) {
                int row = m0 + wr + fm * 16 + g * 4 + r;
                int col = n0 + wc + fn * 16 + l15;
                out[(size_t)row * 1024 + col] = acc[fm][fn][r];
            }
}

// ---------------------------------------------------------------------------
extern "C" void kernel_launch(void* const* d_in, const int* in_sizes, int n_in,
                              void* d_out, int out_size, void* d_ws, size_t ws_size,
                              hipStream_t stream)
{
    const float* hidden = (const float*)d_in[0];
    const float* wqkv   = (const float*)d_in[1];
    const float* wout   = (const float*)d_in[2];
    float* out = (float*)d_out;

    const size_t NELEM = (size_t)2 * SEQ * HID;   // 4,194,304
    ushort* Qb    = (ushort*)d_ws;
    ushort* Kb    = Qb + NELEM;
    ushort* Vb    = Kb + NELEM;
    ushort* hbf   = Vb + NELEM;                   // hidden bf16; later reused as attn
    ushort* wqkvT = hbf + NELEM;                  // 3072*1024
    ushort* woutT = wqkvT + (size_t)3072 * 1024;  // 1024*1024
    ushort* attnb = hbf;                          // alias: lifetime disjoint

    convert_bf16_kernel<<<2048, 256, 0, stream>>>(hidden, hbf, (int)NELEM);
    transpose_bf16_kernel<<<dim3(48, 16), 256, 0, stream>>>(wqkv, wqkvT, 1024, 3072);
    transpose_bf16_kernel<<<dim3(16, 16), 256, 0, stream>>>(wout, woutT, 1024, 1024);
    qkv_rope_kernel<<<dim3(24, 32), 256, 0, stream>>>(hbf, wqkvT, Qb, Kb, Vb);
    attn_kernel<<<dim3(16, NHEADS, 2), 256, 0, stream>>>(Qb, Kb, Vb, attnb);
    out_proj_kernel<<<dim3(8, 32), 256, 0, stream>>>(attnb, woutT, out);
}

// Round 5
// 167.273 us; speedup vs baseline: 2.0517x; 1.1063x over previous
//
#include <hip/hip_runtime.h>

#define SEQ   2048
#define NHEADS 16
#define HDIM  64
#define HID   1024
#define ROT   32

typedef __attribute__((ext_vector_type(8))) short  short8;
typedef __attribute__((ext_vector_type(4))) float  floatx4;

__device__ __forceinline__ ushort f2bf(float f) {
    union { float f; uint u; } v; v.f = f;
    uint x = v.u;
    uint r = (x + 0x7FFFu + ((x >> 16) & 1u)) >> 16;
    return (ushort)r;
}

__device__ __forceinline__ floatx4 mfma_bf16(short8 a, short8 b, floatx4 c) {
    return __builtin_amdgcn_mfma_f32_16x16x32_bf16(a, b, c, 0, 0, 0);
}

__device__ __forceinline__ void gload16(const ushort* g, ushort* l) {
    __builtin_amdgcn_global_load_lds(
        (const __attribute__((address_space(1))) void*)g,
        (__attribute__((address_space(3))) void*)l, 16, 0, 0);
}

// ---------------------------------------------------------------------------
// Pre-pass A: fp32 -> bf16 elementwise (hidden)
// ---------------------------------------------------------------------------
__global__ __launch_bounds__(256) void convert_bf16_kernel(
    const float* __restrict__ src, ushort* __restrict__ dst, int n)
{
    int i = (blockIdx.x * 256 + threadIdx.x) * 8;
    if (i >= n) return;
    float4 a = *(const float4*)(src + i);
    float4 b = *(const float4*)(src + i + 4);
    short8 v;
    v[0] = (short)f2bf(a.x); v[1] = (short)f2bf(a.y);
    v[2] = (short)f2bf(a.z); v[3] = (short)f2bf(a.w);
    v[4] = (short)f2bf(b.x); v[5] = (short)f2bf(b.y);
    v[6] = (short)f2bf(b.z); v[7] = (short)f2bf(b.w);
    *(short8*)(dst + i) = v;
}

// ---------------------------------------------------------------------------
// Pre-pass B: fp32 (K,N) -> bf16 (N,K) transpose-convert. Tile 64x64.
// ---------------------------------------------------------------------------
__global__ __launch_bounds__(256) void transpose_bf16_kernel(
    const float* __restrict__ src, ushort* __restrict__ dst, int K, int N)
{
    __shared__ ushort Tl[64 * 68];
    const int k0 = blockIdx.y * 64, n0 = blockIdx.x * 64;
    const int tid = threadIdx.x;
    #pragma unroll
    for (int i = 0; i < 4; i++) {
        int lin = tid + 256 * i;
        int row = lin >> 4;
        int c4  = (lin & 15) * 4;
        float4 v = *(const float4*)(src + (size_t)(k0 + row) * N + n0 + c4);
        uint2 u;
        u.x = (uint)f2bf(v.x) | ((uint)f2bf(v.y) << 16);
        u.y = (uint)f2bf(v.z) | ((uint)f2bf(v.w) << 16);
        *(uint2*)&Tl[row * 68 + c4] = u;
    }
    __syncthreads();
    #pragma unroll
    for (int j = 0; j < 2; j++) {
        int lin = tid + 256 * j;
        int n = lin >> 3, c = lin & 7;
        short8 v;
        #pragma unroll
        for (int u = 0; u < 8; u++) v[u] = (short)Tl[(c * 8 + u) * 68 + n];
        *(short8*)(dst + (size_t)(n0 + n) * K + k0 + c * 8) = v;
    }
}

// ---------------------------------------------------------------------------
// Kernel 1: qkv = hidden @ w_qkv (M=4096, N=3072, K=1024) bf16 inputs,
// m97 structure. Fused RoPE + head-split epilogue. Q pre-scaled by 0.125.
// Q,K (b,h,s,d); V (b,h,d,s).
// ---------------------------------------------------------------------------
__global__ __launch_bounds__(256) void qkv_rope_kernel(
    const ushort* __restrict__ hbf,     // (4096,1024) bf16
    const ushort* __restrict__ wqkvT,   // (3072,1024) bf16 (N,K)
    ushort* __restrict__ Qb, ushort* __restrict__ Kb, ushort* __restrict__ Vb)
{
    __shared__ ushort Al[128 * 32];
    __shared__ ushort Bl[128 * 32];
    const int tid  = threadIdx.x;
    const int lane = tid & 63;
    const int wv   = tid >> 6;
    const int g    = lane >> 4;
    const int l15  = lane & 15;
    const int m0 = blockIdx.y * 128;
    const int n0 = blockIdx.x * 128;
    const int wr = (wv >> 1) * 64;
    const int wc = (wv & 1) * 64;
    const int rowl = lane >> 2;
    const int kcol = (lane & 3) * 8;

    floatx4 acc[4][4];
    #pragma unroll
    for (int a = 0; a < 4; a++)
        #pragma unroll
        for (int bq = 0; bq < 4; bq++)
            acc[a][bq] = floatx4{0.f, 0.f, 0.f, 0.f};

    const ushort* ga = hbf   + (size_t)(m0 + wv * 32 + rowl) * 1024 + kcol;
    const ushort* gb = wqkvT + (size_t)(n0 + wv * 32 + rowl) * 1024 + kcol;
    ushort* lA = &Al[wv * 1024];
    ushort* lB = &Bl[wv * 1024];

    for (int k0 = 0; k0 < 1024; k0 += 32) {
        gload16(ga + k0,             lA);
        gload16(ga + k0 + 16 * 1024, lA + 512);
        gload16(gb + k0,             lB);
        gload16(gb + k0 + 16 * 1024, lB + 512);
        __syncthreads();
        short8 af[4], bfr[4];
        #pragma unroll
        for (int fm = 0; fm < 4; fm++)
            af[fm] = *(const short8*)&Al[(wr + fm * 16 + l15) * 32 + g * 8];
        #pragma unroll
        for (int fn = 0; fn < 4; fn++)
            bfr[fn] = *(const short8*)&Bl[(wc + fn * 16 + l15) * 32 + g * 8];
        #pragma unroll
        for (int fm = 0; fm < 4; fm++)
            #pragma unroll
            for (int fn = 0; fn < 4; fn++)
                acc[fm][fn] = mfma_bf16(af[fm], bfr[fn], acc[fm][fn]);
        __syncthreads();
    }

    #pragma unroll
    for (int fn = 0; fn < 4; fn++) {
        const int c    = n0 + wc + fn * 16 + l15;
        const int mp   = c / 384;
        const int rem  = c - mp * 384;
        const int tsel = rem >> 7;                    // 0=q 1=k 2=v
        const int j    = (rem >> 6) & 1;
        const int d    = rem & 63;
        const int head = mp * 2 + j;
        ushort* basep = (tsel == 0) ? Qb : (tsel == 1) ? Kb : Vb;
        const bool rope = (tsel < 2) && (d < ROT);
        const float qscale = (tsel == 0) ? 0.125f : 1.0f;
        float freq = 0.f;
        if (rope) {
            freq = exp2f((float)(d >> 1) * -0.830482023721841f);
        }
        #pragma unroll
        for (int fm = 0; fm < 4; fm++) {
            #pragma unroll
            for (int r = 0; r < 4; r++) {
                int row = m0 + wr + fm * 16 + g * 4 + r;
                int bb  = row >> 11;
                int s   = row & 2047;
                float val = acc[fm][fn][r];
                float pv  = __shfl_xor(val, 1, 64);
                float outv = val;
                if (rope) {
                    float ang = (float)s * freq;
                    float sn, cs;
                    sincosf(ang, &sn, &cs);
                    outv = ((d & 1) == 0) ? (val * cs - pv * sn)
                                          : (val * cs + pv * sn);
                }
                outv *= qscale;
                size_t off;
                if (tsel == 2)
                    off = ((size_t)(bb * NHEADS + head) * HDIM + d) * SEQ + s;
                else
                    off = ((size_t)(bb * NHEADS + head) * SEQ + s) * HDIM + d;
                basep[off] = f2bf(outv);
            }
        }
    }
}

// ---------------------------------------------------------------------------
// Kernel 2: flash attention, causal. 128 q-rows/WG, 4 waves, KV tiles 64.
// Complementary-qb dispatch pairing (WG w and w+256 -> same CU get qb summing
// to 15 => every CU gets exactly 34 tiles). 2-deep register prefetch + LDS
// double-buffer. Defer-max, cvt_pk P-pack, setprio. Q pre-scaled by 0.125.
// ---------------------------------------------------------------------------
__global__ __launch_bounds__(256) void attn_kernel(
    const ushort* __restrict__ Qb, const ushort* __restrict__ Kb,
    const ushort* __restrict__ Vb, ushort* __restrict__ attn)
{
    __shared__ ushort Kl[2][64 * 72];      // [key][d], stride 72
    __shared__ ushort Vt[2][64 * 72];      // [d][key], stride 72

    const int tid  = threadIdx.x;
    const int lane = tid & 63;
    const int wv   = tid >> 6;
    const int g    = lane >> 4;
    const int l15  = lane & 15;

    // complementary pairing: WG l and l+256 land on the same CU under
    // round-robin dispatch; give them qb = 15-x and x (sum 15 => equal work).
    const int l    = blockIdx.x + 16 * blockIdx.y + 256 * blockIdx.z;
    const int half = l >> 8;
    const int xx   = l & 15;
    const int hh   = (l >> 4) & 15;
    const int qb   = half ? xx : 15 - xx;
    const int bb   = half;

    const int q0 = qb * 128;
    const int wq = wv * 32;
    const size_t kvbase = (size_t)(bb * NHEADS + hh) * SEQ * HDIM;

    const int srow = tid >> 3;             // 0..31 staging row (plus +32)
    const int sch  = (tid & 7) * 8;        // staging col (ushort)

    short8 qreg[2][2];
    #pragma unroll
    for (int qf = 0; qf < 2; qf++)
        #pragma unroll
        for (int ks = 0; ks < 2; ks++)
            qreg[qf][ks] = *(const short8*)(Qb + kvbase +
                (size_t)(q0 + wq + qf * 16 + l15) * HDIM + ks * 32 + g * 8);

    float m[2], lsum[2];
    floatx4 of[2][4];
    #pragma unroll
    for (int qf = 0; qf < 2; qf++) { m[qf] = -__builtin_inff(); lsum[qf] = 0.f; }
    #pragma unroll
    for (int mf = 0; mf < 2; mf++)
        #pragma unroll
        for (int df = 0; df < 4; df++)
            of[mf][df] = floatx4{0.f, 0.f, 0.f, 0.f};

    const int nt = 2 * qb + 2;             // always even

    auto load_tile = [&](int tt, short8* kr, short8* vr) {
        const int kv = tt * 64;
        #pragma unroll
        for (int i = 0; i < 2; i++) {
            kr[i] = *(const short8*)(Kb + kvbase + (size_t)(kv + srow + 32 * i) * HDIM + sch);
            vr[i] = *(const short8*)(Vb + kvbase + (size_t)(srow + 32 * i) * SEQ + kv + sch);
        }
    };
    auto write_tile = [&](int buf, short8* kr, short8* vr) {
        #pragma unroll
        for (int i = 0; i < 2; i++) {
            *(short8*)&Kl[buf][(srow + 32 * i) * 72 + sch] = kr[i];
            *(short8*)&Vt[buf][(srow + 32 * i) * 72 + sch] = vr[i];
        }
    };
    auto compute_tile = [&](int t, const ushort* Kc, const ushort* Vc) {
        const int kv0 = t * 64;
        if (kv0 > q0 + wq + 31) return;    // fully-masked for this wave
        // QK^T (swapped): sf[kf][qf], lane l15 = q, key = kf*16 + g*4 + r
        floatx4 sf[4][2];
        __builtin_amdgcn_s_setprio(1);
        #pragma unroll
        for (int kf = 0; kf < 4; kf++) {
            short8 kr0 = *(const short8*)&Kc[(kf * 16 + l15) * 72 + g * 8];
            short8 kr1 = *(const short8*)&Kc[(kf * 16 + l15) * 72 + 32 + g * 8];
            #pragma unroll
            for (int qf = 0; qf < 2; qf++) {
                floatx4 s = floatx4{0.f, 0.f, 0.f, 0.f};
                s = mfma_bf16(kr0, qreg[qf][0], s);
                s = mfma_bf16(kr1, qreg[qf][1], s);
                sf[kf][qf] = s;
            }
        }
        __builtin_amdgcn_s_setprio(0);

        const bool diag = (kv0 + 63 > q0 + wq);   // wave-uniform
        float f[2];
        int resc[2];
        #pragma unroll
        for (int qf = 0; qf < 2; qf++) {
            const int qg = q0 + wq + qf * 16 + l15;
            float tmax = -__builtin_inff();
            if (diag) {
                #pragma unroll
                for (int kf = 0; kf < 4; kf++) {
                    #pragma unroll
                    for (int r = 0; r < 4; r++) {
                        int key = kv0 + kf * 16 + g * 4 + r;
                        float x = sf[kf][qf][r];
                        if (key > qg) x = -1e9f;
                        sf[kf][qf][r] = x;
                        tmax = fmaxf(tmax, x);
                    }
                }
            } else {
                #pragma unroll
                for (int kf = 0; kf < 4; kf++)
                    #pragma unroll
                    for (int r = 0; r < 4; r++)
                        tmax = fmaxf(tmax, sf[kf][qf][r]);
            }
            tmax = fmaxf(tmax, __shfl_xor(tmax, 16, 64));
            tmax = fmaxf(tmax, __shfl_xor(tmax, 32, 64));
            resc[qf] = !__all(tmax <= m[qf] + 8.0f);
            float mn = m[qf];
            if (resc[qf]) {
                mn = fmaxf(m[qf], tmax);
                f[qf] = __expf(m[qf] - mn);
                m[qf] = mn;
            } else {
                f[qf] = 1.0f;
            }
            float rs = 0.f;
            #pragma unroll
            for (int kf = 0; kf < 4; kf++) {
                #pragma unroll
                for (int r = 0; r < 4; r++) {
                    float p = __expf(sf[kf][qf][r] - mn);
                    sf[kf][qf][r] = p;
                    rs += p;
                }
            }
            rs += __shfl_xor(rs, 16, 64);
            rs += __shfl_xor(rs, 32, 64);
            lsum[qf] = lsum[qf] * f[qf] + rs;
        }
        // pack P into lane-local A-frags via v_cvt_pk_bf16_f32
        short8 pa[2][2];
        #pragma unroll
        for (int qf = 0; qf < 2; qf++) {
            #pragma unroll
            for (int ks = 0; ks < 2; ks++) {
                union { short8 s; uint u[4]; } pu;
                #pragma unroll
                for (int w = 0; w < 4; w++) {
                    const int kf = 2 * ks + (w >> 1);
                    float lo = sf[kf][qf][(w & 1) * 2 + 0];
                    float hi = sf[kf][qf][(w & 1) * 2 + 1];
                    asm("v_cvt_pk_bf16_f32 %0, %1, %2"
                        : "=v"(pu.u[w]) : "v"(lo), "v"(hi));
                }
                pa[qf][ks] = pu.s;
            }
        }
        if (resc[0] | resc[1]) {
            #pragma unroll
            for (int mf = 0; mf < 2; mf++) {
                if (resc[mf]) {
                    #pragma unroll
                    for (int r = 0; r < 4; r++) {
                        float fr = __shfl(f[mf], g * 4 + r, 64);
                        #pragma unroll
                        for (int df = 0; df < 4; df++)
                            of[mf][df][r] *= fr;
                    }
                }
            }
        }
        // PV
        __builtin_amdgcn_s_setprio(1);
        #pragma unroll
        for (int df = 0; df < 4; df++) {
            #pragma unroll
            for (int ks = 0; ks < 2; ks++) {
                const int vb = (df * 16 + l15) * 72 + ks * 32 + g * 4;
                uint2 v0 = *(const uint2*)&Vc[vb];
                uint2 v1 = *(const uint2*)&Vc[vb + 16];
                union { short8 s; uint4 u; } vv;
                vv.u.x = v0.x; vv.u.y = v0.y; vv.u.z = v1.x; vv.u.w = v1.y;
                #pragma unroll
                for (int mf = 0; mf < 2; mf++)
                    of[mf][df] = mfma_bf16(pa[mf][ks], vv.s, of[mf][df]);
            }
        }
        __builtin_amdgcn_s_setprio(0);
    };

    // 2-deep prefetch pipeline (nt even, so the x2 unroll has no tail)
    short8 kA[2], vA[2], kB[2], vB[2];
    load_tile(0, kA, vA);
    if (nt > 1) load_tile(1, kB, vB);
    write_tile(0, kA, vA);
    __syncthreads();

    for (int t = 0; t < nt; t += 2) {
        if (t + 2 < nt) load_tile(t + 2, kA, vA);
        compute_tile(t, Kl[0], Vt[0]);
        write_tile(1, kB, vB);
        __syncthreads();
        if (t + 3 < nt) load_tile(t + 3, kB, vB);
        compute_tile(t + 1, Kl[1], Vt[1]);
        if (t + 2 < nt) write_tile(0, kA, vA);
        __syncthreads();
    }

    // epilogue: O /= l, store attn (b, s, H) bf16
    #pragma unroll
    for (int mf = 0; mf < 2; mf++) {
        #pragma unroll
        for (int r = 0; r < 4; r++) {
            float lr = __shfl(lsum[mf], g * 4 + r, 64);
            float inv = 1.0f / lr;
            int q = q0 + wq + mf * 16 + g * 4 + r;
            #pragma unroll
            for (int df = 0; df < 4; df++)
                attn[((size_t)bb * SEQ + q) * HID + hh * 64 + df * 16 + l15] =
                    f2bf(of[mf][df][r] * inv);
        }
    }
}

// ---------------------------------------------------------------------------
// Kernel 3: out = attn @ w_out (M=4096, N=1024, K=1024), m97 structure.
// ---------------------------------------------------------------------------
__global__ __launch_bounds__(256) void out_proj_kernel(
    const ushort* __restrict__ attn,    // (4096,1024) bf16
    const ushort* __restrict__ woutT,   // (1024,1024) bf16 (N,K)
    float* __restrict__ out)
{
    __shared__ ushort Al[128 * 32];
    __shared__ ushort Bl[128 * 32];
    const int tid  = threadIdx.x;
    const int lane = tid & 63;
    const int wv   = tid >> 6;
    const int g    = lane >> 4;
    const int l15  = lane & 15;
    const int m0 = blockIdx.y * 128;
    const int n0 = blockIdx.x * 128;
    const int wr = (wv >> 1) * 64;
    const int wc = (wv & 1) * 64;
    const int rowl = lane >> 2;
    const int kcol = (lane & 3) * 8;

    floatx4 acc[4][4];
    #pragma unroll
    for (int a = 0; a < 4; a++)
        #pragma unroll
        for (int bq = 0; bq < 4; bq++)
            acc[a][bq] = floatx4{0.f, 0.f, 0.f, 0.f};

    const ushort* ga = attn  + (size_t)(m0 + wv * 32 + rowl) * 1024 + kcol;
    const ushort* gb = woutT + (size_t)(n0 + wv * 32 + rowl) * 1024 + kcol;
    ushort* lA = &Al[wv * 1024];
    ushort* lB = &Bl[wv * 1024];

    for (int k0 = 0; k0 < 1024; k0 += 32) {
        gload16(ga + k0,             lA);
        gload16(ga + k0 + 16 * 1024, lA + 512);
        gload16(gb + k0,             lB);
        gload16(gb + k0 + 16 * 1024, lB + 512);
        __syncthreads();
        short8 af[4], bfr[4];
        #pragma unroll
        for (int fm = 0; fm < 4; fm++)
            af[fm] = *(const short8*)&Al[(wr + fm * 16 + l15) * 32 + g * 8];
        #pragma unroll
        for (int fn = 0; fn < 4; fn++)
            bfr[fn] = *(const short8*)&Bl[(wc + fn * 16 + l15) * 32 + g * 8];
        #pragma unroll
        for (int fm = 0; fm < 4; fm++)
            #pragma unroll
            for (int fn = 0; fn < 4; fn++)
                acc[fm][fn] = mfma_bf16(af[fm], bfr[fn], acc[fm][fn]);
        __syncthreads();
    }
    #pragma unroll
    for (int fm = 0; fm < 4; fm++)
        #pragma unroll
        for (int fn = 0; fn < 4; fn++)
            #pragma unroll
            for (int r = 0; r < 4; r++) {
                int row = m0 + wr + fm * 16 + g * 4 + r;
                int col = n0 + wc + fn * 16 + l15;
                out[(size_t)row * 1024 + col] = acc[fm][fn][r];
            }
}

// ---------------------------------------------------------------------------
extern "C" void kernel_launch(void* const* d_in, const int* in_sizes, int n_in,
                              void* d_out, int out_size, void* d_ws, size_t ws_size,
                              hipStream_t stream)
{
    const float* hidden = (const float*)d_in[0];
    const float* wqkv   = (const float*)d_in[1];
    const float* wout   = (const float*)d_in[2];
    float* out = (float*)d_out;

    const size_t NELEM = (size_t)2 * SEQ * HID;   // 4,194,304
    ushort* Qb    = (ushort*)d_ws;
    ushort* Kb    = Qb + NELEM;
    ushort* Vb    = Kb + NELEM;
    ushort* hbf   = Vb + NELEM;                   // hidden bf16; later reused as attn
    ushort* wqkvT = hbf + NELEM;                  // 3072*1024
    ushort* woutT = wqkvT + (size_t)3072 * 1024;  // 1024*1024
    ushort* attnb = hbf;                          // alias: lifetime disjoint

    convert_bf16_kernel<<<2048, 256, 0, stream>>>(hidden, hbf, (int)NELEM);
    transpose_bf16_kernel<<<dim3(48, 16), 256, 0, stream>>>(wqkv, wqkvT, 1024, 3072);
    transpose_bf16_kernel<<<dim3(16, 16), 256, 0, stream>>>(wout, woutT, 1024, 1024);
    qkv_rope_kernel<<<dim3(24, 32), 256, 0, stream>>>(hbf, wqkvT, Qb, Kb, Vb);
    attn_kernel<<<dim3(16, NHEADS, 2), 256, 0, stream>>>(Qb, Kb, Vb, attnb);
    out_proj_kernel<<<dim3(8, 32), 256, 0, stream>>>(attnb, woutT, out);
}

// Round 6
// 165.372 us; speedup vs baseline: 2.0752x; 1.0115x over previous
//
#include <hip/hip_runtime.h>

#define SEQ   2048
#define NHEADS 16
#define HDIM  64
#define HID   1024
#define ROT   32

typedef __attribute__((ext_vector_type(8))) short  short8;
typedef __attribute__((ext_vector_type(4))) float  floatx4;

__device__ __forceinline__ ushort f2bf(float f) {
    union { float f; uint u; } v; v.f = f;
    uint x = v.u;
    uint r = (x + 0x7FFFu + ((x >> 16) & 1u)) >> 16;
    return (ushort)r;
}

__device__ __forceinline__ floatx4 mfma_bf16(short8 a, short8 b, floatx4 c) {
    return __builtin_amdgcn_mfma_f32_16x16x32_bf16(a, b, c, 0, 0, 0);
}

__device__ __forceinline__ void gload16(const ushort* g, ushort* l) {
    __builtin_amdgcn_global_load_lds(
        (const __attribute__((address_space(1))) void*)g,
        (__attribute__((address_space(3))) void*)l, 16, 0, 0);
}

// ---------------------------------------------------------------------------
// Pre-pass A: fp32 -> bf16 elementwise (hidden)
// ---------------------------------------------------------------------------
__global__ __launch_bounds__(256) void convert_bf16_kernel(
    const float* __restrict__ src, ushort* __restrict__ dst, int n)
{
    int i = (blockIdx.x * 256 + threadIdx.x) * 8;
    if (i >= n) return;
    float4 a = *(const float4*)(src + i);
    float4 b = *(const float4*)(src + i + 4);
    short8 v;
    v[0] = (short)f2bf(a.x); v[1] = (short)f2bf(a.y);
    v[2] = (short)f2bf(a.z); v[3] = (short)f2bf(a.w);
    v[4] = (short)f2bf(b.x); v[5] = (short)f2bf(b.y);
    v[6] = (short)f2bf(b.z); v[7] = (short)f2bf(b.w);
    *(short8*)(dst + i) = v;
}

// ---------------------------------------------------------------------------
// Pre-pass B: fp32 (K,N) -> bf16 (N,K) transpose-convert. Tile 64x64.
// ---------------------------------------------------------------------------
__global__ __launch_bounds__(256) void transpose_bf16_kernel(
    const float* __restrict__ src, ushort* __restrict__ dst, int K, int N)
{
    __shared__ ushort Tl[64 * 68];
    const int k0 = blockIdx.y * 64, n0 = blockIdx.x * 64;
    const int tid = threadIdx.x;
    #pragma unroll
    for (int i = 0; i < 4; i++) {
        int lin = tid + 256 * i;
        int row = lin >> 4;
        int c4  = (lin & 15) * 4;
        float4 v = *(const float4*)(src + (size_t)(k0 + row) * N + n0 + c4);
        uint2 u;
        u.x = (uint)f2bf(v.x) | ((uint)f2bf(v.y) << 16);
        u.y = (uint)f2bf(v.z) | ((uint)f2bf(v.w) << 16);
        *(uint2*)&Tl[row * 68 + c4] = u;
    }
    __syncthreads();
    #pragma unroll
    for (int j = 0; j < 2; j++) {
        int lin = tid + 256 * j;
        int n = lin >> 3, c = lin & 7;
        short8 v;
        #pragma unroll
        for (int u = 0; u < 8; u++) v[u] = (short)Tl[(c * 8 + u) * 68 + n];
        *(short8*)(dst + (size_t)(n0 + n) * K + k0 + c * 8) = v;
    }
}

// ---------------------------------------------------------------------------
// Kernel 1: qkv = hidden @ w_qkv (M=4096, N=3072, K=1024) bf16 inputs,
// m97 structure + XCD-chunked 2D block remap: each XCD owns a 12x8 sub-grid
// (A-stripe 2MB + B-stripe 3MB ~ L2-resident). Fused RoPE + head split.
// Q pre-scaled by 0.125. Q,K (b,h,s,d); V (b,h,d,s).
// ---------------------------------------------------------------------------
__global__ __launch_bounds__(256) void qkv_rope_kernel(
    const ushort* __restrict__ hbf,     // (4096,1024) bf16
    const ushort* __restrict__ wqkvT,   // (3072,1024) bf16 (N,K)
    ushort* __restrict__ Qb, ushort* __restrict__ Kb, ushort* __restrict__ Vb)
{
    __shared__ ushort Al[128 * 32];
    __shared__ ushort Bl[128 * 32];
    const int tid  = threadIdx.x;
    const int lane = tid & 63;
    const int wv   = tid >> 6;
    const int g    = lane >> 4;
    const int l15  = lane & 15;

    // XCD-chunked remap: lin%8 = XCD (round-robin dispatch); give XCD
    // (cxi,cyi) the 12x8 chunk [cxi*12,+12) x [cyi*8,+8) of the 24x32 grid.
    const int lin  = blockIdx.x + 24 * blockIdx.y;  // 0..767
    const int xcd  = lin & 7;
    const int slot = lin >> 3;                      // 0..95
    const int cxi  = xcd & 1, cyi = xcd >> 1;
    const int sx   = slot % 12, sy = slot / 12;     // 12x8
    const int n0   = (cxi * 12 + sx) * 128;
    const int m0   = (cyi * 8 + sy) * 128;

    const int wr = (wv >> 1) * 64;
    const int wc = (wv & 1) * 64;
    const int rowl = lane >> 2;
    const int kcol = (lane & 3) * 8;

    floatx4 acc[4][4];
    #pragma unroll
    for (int a = 0; a < 4; a++)
        #pragma unroll
        for (int bq = 0; bq < 4; bq++)
            acc[a][bq] = floatx4{0.f, 0.f, 0.f, 0.f};

    const ushort* ga = hbf   + (size_t)(m0 + wv * 32 + rowl) * 1024 + kcol;
    const ushort* gb = wqkvT + (size_t)(n0 + wv * 32 + rowl) * 1024 + kcol;
    ushort* lA = &Al[wv * 1024];
    ushort* lB = &Bl[wv * 1024];

    for (int k0 = 0; k0 < 1024; k0 += 32) {
        gload16(ga + k0,             lA);
        gload16(ga + k0 + 16 * 1024, lA + 512);
        gload16(gb + k0,             lB);
        gload16(gb + k0 + 16 * 1024, lB + 512);
        __syncthreads();
        short8 af[4], bfr[4];
        #pragma unroll
        for (int fm = 0; fm < 4; fm++)
            af[fm] = *(const short8*)&Al[(wr + fm * 16 + l15) * 32 + g * 8];
        #pragma unroll
        for (int fn = 0; fn < 4; fn++)
            bfr[fn] = *(const short8*)&Bl[(wc + fn * 16 + l15) * 32 + g * 8];
        #pragma unroll
        for (int fm = 0; fm < 4; fm++)
            #pragma unroll
            for (int fn = 0; fn < 4; fn++)
                acc[fm][fn] = mfma_bf16(af[fm], bfr[fn], acc[fm][fn]);
        __syncthreads();
    }

    #pragma unroll
    for (int fn = 0; fn < 4; fn++) {
        const int c    = n0 + wc + fn * 16 + l15;
        const int mp   = c / 384;
        const int rem  = c - mp * 384;
        const int tsel = rem >> 7;                    // 0=q 1=k 2=v
        const int j    = (rem >> 6) & 1;
        const int d    = rem & 63;
        const int head = mp * 2 + j;
        ushort* basep = (tsel == 0) ? Qb : (tsel == 1) ? Kb : Vb;
        const bool rope = (tsel < 2) && (d < ROT);
        const float qscale = (tsel == 0) ? 0.125f : 1.0f;
        float freq = 0.f;
        if (rope) {
            freq = exp2f((float)(d >> 1) * -0.830482023721841f);
        }
        #pragma unroll
        for (int fm = 0; fm < 4; fm++) {
            #pragma unroll
            for (int r = 0; r < 4; r++) {
                int row = m0 + wr + fm * 16 + g * 4 + r;
                int bb  = row >> 11;
                int s   = row & 2047;
                float val = acc[fm][fn][r];
                float pv  = __shfl_xor(val, 1, 64);
                float outv = val;
                if (rope) {
                    float ang = (float)s * freq;
                    float sn, cs;
                    sincosf(ang, &sn, &cs);
                    outv = ((d & 1) == 0) ? (val * cs - pv * sn)
                                          : (val * cs + pv * sn);
                }
                outv *= qscale;
                size_t off;
                if (tsel == 2)
                    off = ((size_t)(bb * NHEADS + head) * HDIM + d) * SEQ + s;
                else
                    off = ((size_t)(bb * NHEADS + head) * SEQ + s) * HDIM + d;
                basep[off] = f2bf(outv);
            }
        }
    }
}

// ---------------------------------------------------------------------------
// Kernel 2: flash attention, causal. 128 q-rows/WG, 4 waves, KV tiles 64.
// Complementary-qb dispatch pairing; 2-deep register prefetch + LDS
// double-buffer; defer-max; cvt_pk P-pack; setprio. Q pre-scaled by 0.125.
// ---------------------------------------------------------------------------
__global__ __launch_bounds__(256) void attn_kernel(
    const ushort* __restrict__ Qb, const ushort* __restrict__ Kb,
    const ushort* __restrict__ Vb, ushort* __restrict__ attn)
{
    __shared__ ushort Kl[2][64 * 72];      // [key][d], stride 72
    __shared__ ushort Vt[2][64 * 72];      // [d][key], stride 72

    const int tid  = threadIdx.x;
    const int lane = tid & 63;
    const int wv   = tid >> 6;
    const int g    = lane >> 4;
    const int l15  = lane & 15;

    const int l    = blockIdx.x + 16 * blockIdx.y + 256 * blockIdx.z;
    const int half = l >> 8;
    const int xx   = l & 15;
    const int hh   = (l >> 4) & 15;
    const int qb   = half ? xx : 15 - xx;
    const int bb   = half;

    const int q0 = qb * 128;
    const int wq = wv * 32;
    const size_t kvbase = (size_t)(bb * NHEADS + hh) * SEQ * HDIM;

    const int srow = tid >> 3;             // 0..31 staging row (plus +32)
    const int sch  = (tid & 7) * 8;        // staging col (ushort)

    short8 qreg[2][2];
    #pragma unroll
    for (int qf = 0; qf < 2; qf++)
        #pragma unroll
        for (int ks = 0; ks < 2; ks++)
            qreg[qf][ks] = *(const short8*)(Qb + kvbase +
                (size_t)(q0 + wq + qf * 16 + l15) * HDIM + ks * 32 + g * 8);

    float m[2], lsum[2];
    floatx4 of[2][4];
    #pragma unroll
    for (int qf = 0; qf < 2; qf++) { m[qf] = -__builtin_inff(); lsum[qf] = 0.f; }
    #pragma unroll
    for (int mf = 0; mf < 2; mf++)
        #pragma unroll
        for (int df = 0; df < 4; df++)
            of[mf][df] = floatx4{0.f, 0.f, 0.f, 0.f};

    const int nt = 2 * qb + 2;             // always even

    auto load_tile = [&](int tt, short8* kr, short8* vr) {
        const int kv = tt * 64;
        #pragma unroll
        for (int i = 0; i < 2; i++) {
            kr[i] = *(const short8*)(Kb + kvbase + (size_t)(kv + srow + 32 * i) * HDIM + sch);
            vr[i] = *(const short8*)(Vb + kvbase + (size_t)(srow + 32 * i) * SEQ + kv + sch);
        }
    };
    auto write_tile = [&](int buf, short8* kr, short8* vr) {
        #pragma unroll
        for (int i = 0; i < 2; i++) {
            *(short8*)&Kl[buf][(srow + 32 * i) * 72 + sch] = kr[i];
            *(short8*)&Vt[buf][(srow + 32 * i) * 72 + sch] = vr[i];
        }
    };
    auto compute_tile = [&](int t, const ushort* Kc, const ushort* Vc) {
        const int kv0 = t * 64;
        if (kv0 > q0 + wq + 31) return;    // fully-masked for this wave
        floatx4 sf[4][2];
        __builtin_amdgcn_s_setprio(1);
        #pragma unroll
        for (int kf = 0; kf < 4; kf++) {
            short8 kr0 = *(const short8*)&Kc[(kf * 16 + l15) * 72 + g * 8];
            short8 kr1 = *(const short8*)&Kc[(kf * 16 + l15) * 72 + 32 + g * 8];
            #pragma unroll
            for (int qf = 0; qf < 2; qf++) {
                floatx4 s = floatx4{0.f, 0.f, 0.f, 0.f};
                s = mfma_bf16(kr0, qreg[qf][0], s);
                s = mfma_bf16(kr1, qreg[qf][1], s);
                sf[kf][qf] = s;
            }
        }
        __builtin_amdgcn_s_setprio(0);

        const bool diag = (kv0 + 63 > q0 + wq);   // wave-uniform
        float f[2];
        int resc[2];
        #pragma unroll
        for (int qf = 0; qf < 2; qf++) {
            const int qg = q0 + wq + qf * 16 + l15;
            float tmax = -__builtin_inff();
            if (diag) {
                #pragma unroll
                for (int kf = 0; kf < 4; kf++) {
                    #pragma unroll
                    for (int r = 0; r < 4; r++) {
                        int key = kv0 + kf * 16 + g * 4 + r;
                        float x = sf[kf][qf][r];
                        if (key > qg) x = -1e9f;
                        sf[kf][qf][r] = x;
                        tmax = fmaxf(tmax, x);
                    }
                }
            } else {
                #pragma unroll
                for (int kf = 0; kf < 4; kf++)
                    #pragma unroll
                    for (int r = 0; r < 4; r++)
                        tmax = fmaxf(tmax, sf[kf][qf][r]);
            }
            tmax = fmaxf(tmax, __shfl_xor(tmax, 16, 64));
            tmax = fmaxf(tmax, __shfl_xor(tmax, 32, 64));
            resc[qf] = !__all(tmax <= m[qf] + 8.0f);
            float mn = m[qf];
            if (resc[qf]) {
                mn = fmaxf(m[qf], tmax);
                f[qf] = __expf(m[qf] - mn);
                m[qf] = mn;
            } else {
                f[qf] = 1.0f;
            }
            float rs = 0.f;
            #pragma unroll
            for (int kf = 0; kf < 4; kf++) {
                #pragma unroll
                for (int r = 0; r < 4; r++) {
                    float p = __expf(sf[kf][qf][r] - mn);
                    sf[kf][qf][r] = p;
                    rs += p;
                }
            }
            rs += __shfl_xor(rs, 16, 64);
            rs += __shfl_xor(rs, 32, 64);
            lsum[qf] = lsum[qf] * f[qf] + rs;
        }
        short8 pa[2][2];
        #pragma unroll
        for (int qf = 0; qf < 2; qf++) {
            #pragma unroll
            for (int ks = 0; ks < 2; ks++) {
                union { short8 s; uint u[4]; } pu;
                #pragma unroll
                for (int w = 0; w < 4; w++) {
                    const int kf = 2 * ks + (w >> 1);
                    float lo = sf[kf][qf][(w & 1) * 2 + 0];
                    float hi = sf[kf][qf][(w & 1) * 2 + 1];
                    asm("v_cvt_pk_bf16_f32 %0, %1, %2"
                        : "=v"(pu.u[w]) : "v"(lo), "v"(hi));
                }
                pa[qf][ks] = pu.s;
            }
        }
        if (resc[0] | resc[1]) {
            #pragma unroll
            for (int mf = 0; mf < 2; mf++) {
                if (resc[mf]) {
                    #pragma unroll
                    for (int r = 0; r < 4; r++) {
                        float fr = __shfl(f[mf], g * 4 + r, 64);
                        #pragma unroll
                        for (int df = 0; df < 4; df++)
                            of[mf][df][r] *= fr;
                    }
                }
            }
        }
        __builtin_amdgcn_s_setprio(1);
        #pragma unroll
        for (int df = 0; df < 4; df++) {
            #pragma unroll
            for (int ks = 0; ks < 2; ks++) {
                const int vb = (df * 16 + l15) * 72 + ks * 32 + g * 4;
                uint2 v0 = *(const uint2*)&Vc[vb];
                uint2 v1 = *(const uint2*)&Vc[vb + 16];
                union { short8 s; uint4 u; } vv;
                vv.u.x = v0.x; vv.u.y = v0.y; vv.u.z = v1.x; vv.u.w = v1.y;
                #pragma unroll
                for (int mf = 0; mf < 2; mf++)
                    of[mf][df] = mfma_bf16(pa[mf][ks], vv.s, of[mf][df]);
            }
        }
        __builtin_amdgcn_s_setprio(0);
    };

    short8 kA[2], vA[2], kB[2], vB[2];
    load_tile(0, kA, vA);
    if (nt > 1) load_tile(1, kB, vB);
    write_tile(0, kA, vA);
    __syncthreads();

    for (int t = 0; t < nt; t += 2) {
        if (t + 2 < nt) load_tile(t + 2, kA, vA);
        compute_tile(t, Kl[0], Vt[0]);
        write_tile(1, kB, vB);
        __syncthreads();
        if (t + 3 < nt) load_tile(t + 3, kB, vB);
        compute_tile(t + 1, Kl[1], Vt[1]);
        if (t + 2 < nt) write_tile(0, kA, vA);
        __syncthreads();
    }

    // epilogue: O /= l, store attn (b, s, H) bf16
    #pragma unroll
    for (int mf = 0; mf < 2; mf++) {
        #pragma unroll
        for (int r = 0; r < 4; r++) {
            float lr = __shfl(lsum[mf], g * 4 + r, 64);
            float inv = 1.0f / lr;
            int q = q0 + wq + mf * 16 + g * 4 + r;
            #pragma unroll
            for (int df = 0; df < 4; df++)
                attn[((size_t)bb * SEQ + q) * HID + hh * 64 + df * 16 + l15] =
                    f2bf(of[mf][df][r] * inv);
        }
    }
}

// ---------------------------------------------------------------------------
// Kernel 3: out = attn @ w_out (M=4096, N=1024, K=1024), m97 structure +
// XCD-chunked remap (4x8 chunks, ~3MB working set per XCD).
// ---------------------------------------------------------------------------
__global__ __launch_bounds__(256) void out_proj_kernel(
    const ushort* __restrict__ attn,    // (4096,1024) bf16
    const ushort* __restrict__ woutT,   // (1024,1024) bf16 (N,K)
    float* __restrict__ out)
{
    __shared__ ushort Al[128 * 32];
    __shared__ ushort Bl[128 * 32];
    const int tid  = threadIdx.x;
    const int lane = tid & 63;
    const int wv   = tid >> 6;
    const int g    = lane >> 4;
    const int l15  = lane & 15;

    const int lin  = blockIdx.x + 8 * blockIdx.y;   // 0..255
    const int xcd  = lin & 7;
    const int slot = lin >> 3;                      // 0..31
    const int cxi  = xcd & 1, cyi = xcd >> 1;
    const int sx   = slot & 3, sy = slot >> 2;      // 4x8
    const int n0   = (cxi * 4 + sx) * 128;
    const int m0   = (cyi * 8 + sy) * 128;

    const int wr = (wv >> 1) * 64;
    const int wc = (wv & 1) * 64;
    const int rowl = lane >> 2;
    const int kcol = (lane & 3) * 8;

    floatx4 acc[4][4];
    #pragma unroll
    for (int a = 0; a < 4; a++)
        #pragma unroll
        for (int bq = 0; bq < 4; bq++)
            acc[a][bq] = floatx4{0.f, 0.f, 0.f, 0.f};

    const ushort* ga = attn  + (size_t)(m0 + wv * 32 + rowl) * 1024 + kcol;
    const ushort* gb = woutT + (size_t)(n0 + wv * 32 + rowl) * 1024 + kcol;
    ushort* lA = &Al[wv * 1024];
    ushort* lB = &Bl[wv * 1024];

    for (int k0 = 0; k0 < 1024; k0 += 32) {
        gload16(ga + k0,             lA);
        gload16(ga + k0 + 16 * 1024, lA + 512);
        gload16(gb + k0,             lB);
        gload16(gb + k0 + 16 * 1024, lB + 512);
        __syncthreads();
        short8 af[4], bfr[4];
        #pragma unroll
        for (int fm = 0; fm < 4; fm++)
            af[fm] = *(const short8*)&Al[(wr + fm * 16 + l15) * 32 + g * 8];
        #pragma unroll
        for (int fn = 0; fn < 4; fn++)
            bfr[fn] = *(const short8*)&Bl[(wc + fn * 16 + l15) * 32 + g * 8];
        #pragma unroll
        for (int fm = 0; fm < 4; fm++)
            #pragma unroll
            for (int fn = 0; fn < 4; fn++)
                acc[fm][fn] = mfma_bf16(af[fm], bfr[fn], acc[fm][fn]);
        __syncthreads();
    }
    #pragma unroll
    for (int fm = 0; fm < 4; fm++)
        #pragma unroll
        for (int fn = 0; fn < 4; fn++)
            #pragma unroll
            for (int r = 0; r < 4; r++) {
                int row = m0 + wr + fm * 16 + g * 4 + r;
                int col = n0 + wc + fn * 16 + l15;
                out[(size_t)row * 1024 + col] = acc[fm][fn][r];
            }
}

// ---------------------------------------------------------------------------
extern "C" void kernel_launch(void* const* d_in, const int* in_sizes, int n_in,
                              void* d_out, int out_size, void* d_ws, size_t ws_size,
                              hipStream_t stream)
{
    const float* hidden = (const float*)d_in[0];
    const float* wqkv   = (const float*)d_in[1];
    const float* wout   = (const float*)d_in[2];
    float* out = (float*)d_out;

    const size_t NELEM = (size_t)2 * SEQ * HID;   // 4,194,304
    ushort* Qb    = (ushort*)d_ws;
    ushort* Kb    = Qb + NELEM;
    ushort* Vb    = Kb + NELEM;
    ushort* hbf   = Vb + NELEM;                   // hidden bf16; later reused as attn
    ushort* wqkvT = hbf + NELEM;                  // 3072*1024
    ushort* woutT = wqkvT + (size_t)3072 * 1024;  // 1024*1024
    ushort* attnb = hbf;                          // alias: lifetime disjoint

    convert_bf16_kernel<<<2048, 256, 0, stream>>>(hidden, hbf, (int)NELEM);
    transpose_bf16_kernel<<<dim3(48, 16), 256, 0, stream>>>(wqkv, wqkvT, 1024, 3072);
    transpose_bf16_kernel<<<dim3(16, 16), 256, 0, stream>>>(wout, woutT, 1024, 1024);
    qkv_rope_kernel<<<dim3(24, 32), 256, 0, stream>>>(hbf, wqkvT, Qb, Kb, Vb);
    attn_kernel<<<dim3(16, NHEADS, 2), 256, 0, stream>>>(Qb, Kb, Vb, attnb);
    out_proj_kernel<<<dim3(8, 32), 256, 0, stream>>>(attnb, woutT, out);
}

// Round 7
// 145.099 us; speedup vs baseline: 2.3652x; 1.1397x over previous
//
#include <hip/hip_runtime.h>

#define SEQ   2048
#define NHEADS 16
#define HDIM  64
#define HID   1024
#define ROT   32

typedef __attribute__((ext_vector_type(8))) short  short8;
typedef __attribute__((ext_vector_type(4))) float  floatx4;

__device__ __forceinline__ ushort f2bf(float f) {
    union { float f; uint u; } v; v.f = f;
    uint x = v.u;
    uint r = (x + 0x7FFFu + ((x >> 16) & 1u)) >> 16;
    return (ushort)r;
}

__device__ __forceinline__ floatx4 mfma_bf16(short8 a, short8 b, floatx4 c) {
    return __builtin_amdgcn_mfma_f32_16x16x32_bf16(a, b, c, 0, 0, 0);
}

__device__ __forceinline__ void gload16(const ushort* g, ushort* l) {
    __builtin_amdgcn_global_load_lds(
        (const __attribute__((address_space(1))) void*)g,
        (__attribute__((address_space(3))) void*)l, 16, 0, 0);
}

// ---------------------------------------------------------------------------
// Pre-pass A: fp32 -> bf16 elementwise (hidden)
// ---------------------------------------------------------------------------
__global__ __launch_bounds__(256) void convert_bf16_kernel(
    const float* __restrict__ src, ushort* __restrict__ dst, int n)
{
    int i = (blockIdx.x * 256 + threadIdx.x) * 8;
    if (i >= n) return;
    float4 a = *(const float4*)(src + i);
    float4 b = *(const float4*)(src + i + 4);
    short8 v;
    v[0] = (short)f2bf(a.x); v[1] = (short)f2bf(a.y);
    v[2] = (short)f2bf(a.z); v[3] = (short)f2bf(a.w);
    v[4] = (short)f2bf(b.x); v[5] = (short)f2bf(b.y);
    v[6] = (short)f2bf(b.z); v[7] = (short)f2bf(b.w);
    *(short8*)(dst + i) = v;
}

// ---------------------------------------------------------------------------
// Pre-pass B: fp32 (K,N) -> bf16 (N,K) transpose-convert. Tile 64x64.
// ---------------------------------------------------------------------------
__global__ __launch_bounds__(256) void transpose_bf16_kernel(
    const float* __restrict__ src, ushort* __restrict__ dst, int K, int N)
{
    __shared__ ushort Tl[64 * 68];
    const int k0 = blockIdx.y * 64, n0 = blockIdx.x * 64;
    const int tid = threadIdx.x;
    #pragma unroll
    for (int i = 0; i < 4; i++) {
        int lin = tid + 256 * i;
        int row = lin >> 4;
        int c4  = (lin & 15) * 4;
        float4 v = *(const float4*)(src + (size_t)(k0 + row) * N + n0 + c4);
        uint2 u;
        u.x = (uint)f2bf(v.x) | ((uint)f2bf(v.y) << 16);
        u.y = (uint)f2bf(v.z) | ((uint)f2bf(v.w) << 16);
        *(uint2*)&Tl[row * 68 + c4] = u;
    }
    __syncthreads();
    #pragma unroll
    for (int j = 0; j < 2; j++) {
        int lin = tid + 256 * j;
        int n = lin >> 3, c = lin & 7;
        short8 v;
        #pragma unroll
        for (int u = 0; u < 8; u++) v[u] = (short)Tl[(c * 8 + u) * 68 + n];
        *(short8*)(dst + (size_t)(n0 + n) * K + k0 + c * 8) = v;
    }
}

// ---------------------------------------------------------------------------
// Kernel 1: qkv = hidden @ w_qkv (M=4096, N=3072, K=1024) bf16 inputs.
// 128^2 tile, BK=32, 2-phase pipelined gload_lds double-buffer:
// issue next tile's loads BEFORE computing current, one vmcnt(0)+raw
// s_barrier per K-step (no __syncthreads drain-before-compute).
// Fused RoPE + head split. Q pre-scaled by 0.125. Q,K (b,h,s,d); V (b,h,d,s).
// ---------------------------------------------------------------------------
__global__ __launch_bounds__(256) void qkv_rope_kernel(
    const ushort* __restrict__ hbf,     // (4096,1024) bf16
    const ushort* __restrict__ wqkvT,   // (3072,1024) bf16 (N,K)
    ushort* __restrict__ Qb, ushort* __restrict__ Kb, ushort* __restrict__ Vb)
{
    __shared__ ushort Al[2][128 * 32];
    __shared__ ushort Bl[2][128 * 32];
    const int tid  = threadIdx.x;
    const int lane = tid & 63;
    const int wv   = tid >> 6;
    const int g    = lane >> 4;
    const int l15  = lane & 15;

    // XCD-chunked remap (kept: neutral-cost, trims FETCH)
    const int lin  = blockIdx.x + 24 * blockIdx.y;  // 0..767
    const int xcd  = lin & 7;
    const int slot = lin >> 3;                      // 0..95
    const int cxi  = xcd & 1, cyi = xcd >> 1;
    const int sx   = slot % 12, sy = slot / 12;     // 12x8
    const int n0   = (cxi * 12 + sx) * 128;
    const int m0   = (cyi * 8 + sy) * 128;

    const int wr = (wv >> 1) * 64;
    const int wc = (wv & 1) * 64;
    const int rowl = lane >> 2;
    const int kcol = (lane & 3) * 8;

    floatx4 acc[4][4];
    #pragma unroll
    for (int a = 0; a < 4; a++)
        #pragma unroll
        for (int bq = 0; bq < 4; bq++)
            acc[a][bq] = floatx4{0.f, 0.f, 0.f, 0.f};

    const ushort* ga = hbf   + (size_t)(m0 + wv * 32 + rowl) * 1024 + kcol;
    const ushort* gb = wqkvT + (size_t)(n0 + wv * 32 + rowl) * 1024 + kcol;
    const int lofs = wv * 1024;

    // prologue: stage tile 0 into buf 0, drain, barrier
    gload16(ga,             &Al[0][lofs]);
    gload16(ga + 16 * 1024, &Al[0][lofs + 512]);
    gload16(gb,             &Bl[0][lofs]);
    gload16(gb + 16 * 1024, &Bl[0][lofs + 512]);
    asm volatile("s_waitcnt vmcnt(0)" ::: "memory");
    __builtin_amdgcn_s_barrier();

    for (int it = 0; it < 32; it++) {
        const int cur = it & 1;
        // issue next tile's staging first (latency hides under compute)
        if (it + 1 < 32) {
            const int k0 = (it + 1) * 32;
            const int nxt = cur ^ 1;
            gload16(ga + k0,             &Al[nxt][lofs]);
            gload16(ga + k0 + 16 * 1024, &Al[nxt][lofs + 512]);
            gload16(gb + k0,             &Bl[nxt][lofs]);
            gload16(gb + k0 + 16 * 1024, &Bl[nxt][lofs + 512]);
        }
        short8 af[4], bfr[4];
        #pragma unroll
        for (int fm = 0; fm < 4; fm++)
            af[fm] = *(const short8*)&Al[cur][(wr + fm * 16 + l15) * 32 + g * 8];
        #pragma unroll
        for (int fn = 0; fn < 4; fn++)
            bfr[fn] = *(const short8*)&Bl[cur][(wc + fn * 16 + l15) * 32 + g * 8];
        #pragma unroll
        for (int fm = 0; fm < 4; fm++)
            #pragma unroll
            for (int fn = 0; fn < 4; fn++)
                acc[fm][fn] = mfma_bf16(af[fm], bfr[fn], acc[fm][fn]);
        // all waves done reading buf[cur]; next tile's loads complete
        asm volatile("s_waitcnt vmcnt(0)" ::: "memory");
        __builtin_amdgcn_s_barrier();
    }

    #pragma unroll
    for (int fn = 0; fn < 4; fn++) {
        const int c    = n0 + wc + fn * 16 + l15;
        const int mp   = c / 384;
        const int rem  = c - mp * 384;
        const int tsel = rem >> 7;                    // 0=q 1=k 2=v
        const int j    = (rem >> 6) & 1;
        const int d    = rem & 63;
        const int head = mp * 2 + j;
        ushort* basep = (tsel == 0) ? Qb : (tsel == 1) ? Kb : Vb;
        const bool rope = (tsel < 2) && (d < ROT);
        const float qscale = (tsel == 0) ? 0.125f : 1.0f;
        float freq = 0.f;
        if (rope) {
            freq = exp2f((float)(d >> 1) * -0.830482023721841f);
        }
        #pragma unroll
        for (int fm = 0; fm < 4; fm++) {
            #pragma unroll
            for (int r = 0; r < 4; r++) {
                int row = m0 + wr + fm * 16 + g * 4 + r;
                int bb  = row >> 11;
                int s   = row & 2047;
                float val = acc[fm][fn][r];
                float pv  = __shfl_xor(val, 1, 64);
                float outv = val;
                if (rope) {
                    float ang = (float)s * freq;
                    float sn, cs;
                    __sincosf(ang, &sn, &cs);
                    outv = ((d & 1) == 0) ? (val * cs - pv * sn)
                                          : (val * cs + pv * sn);
                }
                outv *= qscale;
                size_t off;
                if (tsel == 2)
                    off = ((size_t)(bb * NHEADS + head) * HDIM + d) * SEQ + s;
                else
                    off = ((size_t)(bb * NHEADS + head) * SEQ + s) * HDIM + d;
                basep[off] = f2bf(outv);
            }
        }
    }
}

// ---------------------------------------------------------------------------
// Kernel 2: flash attention, causal. 128 q-rows/WG, 4 waves, KV tiles 64.
// Complementary-qb dispatch pairing; 2-deep register prefetch + LDS
// double-buffer; defer-max; cvt_pk P-pack; setprio. Q pre-scaled by 0.125.
// ---------------------------------------------------------------------------
__global__ __launch_bounds__(256) void attn_kernel(
    const ushort* __restrict__ Qb, const ushort* __restrict__ Kb,
    const ushort* __restrict__ Vb, ushort* __restrict__ attn)
{
    __shared__ ushort Kl[2][64 * 72];      // [key][d], stride 72
    __shared__ ushort Vt[2][64 * 72];      // [d][key], stride 72

    const int tid  = threadIdx.x;
    const int lane = tid & 63;
    const int wv   = tid >> 6;
    const int g    = lane >> 4;
    const int l15  = lane & 15;

    const int l    = blockIdx.x + 16 * blockIdx.y + 256 * blockIdx.z;
    const int half = l >> 8;
    const int xx   = l & 15;
    const int hh   = (l >> 4) & 15;
    const int qb   = half ? xx : 15 - xx;
    const int bb   = half;

    const int q0 = qb * 128;
    const int wq = wv * 32;
    const size_t kvbase = (size_t)(bb * NHEADS + hh) * SEQ * HDIM;

    const int srow = tid >> 3;             // 0..31 staging row (plus +32)
    const int sch  = (tid & 7) * 8;        // staging col (ushort)

    short8 qreg[2][2];
    #pragma unroll
    for (int qf = 0; qf < 2; qf++)
        #pragma unroll
        for (int ks = 0; ks < 2; ks++)
            qreg[qf][ks] = *(const short8*)(Qb + kvbase +
                (size_t)(q0 + wq + qf * 16 + l15) * HDIM + ks * 32 + g * 8);

    float m[2], lsum[2];
    floatx4 of[2][4];
    #pragma unroll
    for (int qf = 0; qf < 2; qf++) { m[qf] = -__builtin_inff(); lsum[qf] = 0.f; }
    #pragma unroll
    for (int mf = 0; mf < 2; mf++)
        #pragma unroll
        for (int df = 0; df < 4; df++)
            of[mf][df] = floatx4{0.f, 0.f, 0.f, 0.f};

    const int nt = 2 * qb + 2;             // always even

    auto load_tile = [&](int tt, short8* kr, short8* vr) {
        const int kv = tt * 64;
        #pragma unroll
        for (int i = 0; i < 2; i++) {
            kr[i] = *(const short8*)(Kb + kvbase + (size_t)(kv + srow + 32 * i) * HDIM + sch);
            vr[i] = *(const short8*)(Vb + kvbase + (size_t)(srow + 32 * i) * SEQ + kv + sch);
        }
    };
    auto write_tile = [&](int buf, short8* kr, short8* vr) {
        #pragma unroll
        for (int i = 0; i < 2; i++) {
            *(short8*)&Kl[buf][(srow + 32 * i) * 72 + sch] = kr[i];
            *(short8*)&Vt[buf][(srow + 32 * i) * 72 + sch] = vr[i];
        }
    };
    auto compute_tile = [&](int t, const ushort* Kc, const ushort* Vc) {
        const int kv0 = t * 64;
        if (kv0 > q0 + wq + 31) return;    // fully-masked for this wave
        floatx4 sf[4][2];
        __builtin_amdgcn_s_setprio(1);
        #pragma unroll
        for (int kf = 0; kf < 4; kf++) {
            short8 kr0 = *(const short8*)&Kc[(kf * 16 + l15) * 72 + g * 8];
            short8 kr1 = *(const short8*)&Kc[(kf * 16 + l15) * 72 + 32 + g * 8];
            #pragma unroll
            for (int qf = 0; qf < 2; qf++) {
                floatx4 s = floatx4{0.f, 0.f, 0.f, 0.f};
                s = mfma_bf16(kr0, qreg[qf][0], s);
                s = mfma_bf16(kr1, qreg[qf][1], s);
                sf[kf][qf] = s;
            }
        }
        __builtin_amdgcn_s_setprio(0);

        const bool diag = (kv0 + 63 > q0 + wq);   // wave-uniform
        float f[2];
        int resc[2];
        #pragma unroll
        for (int qf = 0; qf < 2; qf++) {
            const int qg = q0 + wq + qf * 16 + l15;
            float tmax = -__builtin_inff();
            if (diag) {
                #pragma unroll
                for (int kf = 0; kf < 4; kf++) {
                    #pragma unroll
                    for (int r = 0; r < 4; r++) {
                        int key = kv0 + kf * 16 + g * 4 + r;
                        float x = sf[kf][qf][r];
                        if (key > qg) x = -1e9f;
                        sf[kf][qf][r] = x;
                        tmax = fmaxf(tmax, x);
                    }
                }
            } else {
                #pragma unroll
                for (int kf = 0; kf < 4; kf++)
                    #pragma unroll
                    for (int r = 0; r < 4; r++)
                        tmax = fmaxf(tmax, sf[kf][qf][r]);
            }
            tmax = fmaxf(tmax, __shfl_xor(tmax, 16, 64));
            tmax = fmaxf(tmax, __shfl_xor(tmax, 32, 64));
            resc[qf] = !__all(tmax <= m[qf] + 8.0f);
            float mn = m[qf];
            if (resc[qf]) {
                mn = fmaxf(m[qf], tmax);
                f[qf] = __expf(m[qf] - mn);
                m[qf] = mn;
            } else {
                f[qf] = 1.0f;
            }
            float rs = 0.f;
            #pragma unroll
            for (int kf = 0; kf < 4; kf++) {
                #pragma unroll
                for (int r = 0; r < 4; r++) {
                    float p = __expf(sf[kf][qf][r] - mn);
                    sf[kf][qf][r] = p;
                    rs += p;
                }
            }
            rs += __shfl_xor(rs, 16, 64);
            rs += __shfl_xor(rs, 32, 64);
            lsum[qf] = lsum[qf] * f[qf] + rs;
        }
        short8 pa[2][2];
        #pragma unroll
        for (int qf = 0; qf < 2; qf++) {
            #pragma unroll
            for (int ks = 0; ks < 2; ks++) {
                union { short8 s; uint u[4]; } pu;
                #pragma unroll
                for (int w = 0; w < 4; w++) {
                    const int kf = 2 * ks + (w >> 1);
                    float lo = sf[kf][qf][(w & 1) * 2 + 0];
                    float hi = sf[kf][qf][(w & 1) * 2 + 1];
                    asm("v_cvt_pk_bf16_f32 %0, %1, %2"
                        : "=v"(pu.u[w]) : "v"(lo), "v"(hi));
                }
                pa[qf][ks] = pu.s;
            }
        }
        if (resc[0] | resc[1]) {
            #pragma unroll
            for (int mf = 0; mf < 2; mf++) {
                if (resc[mf]) {
                    #pragma unroll
                    for (int r = 0; r < 4; r++) {
                        float fr = __shfl(f[mf], g * 4 + r, 64);
                        #pragma unroll
                        for (int df = 0; df < 4; df++)
                            of[mf][df][r] *= fr;
                    }
                }
            }
        }
        __builtin_amdgcn_s_setprio(1);
        #pragma unroll
        for (int df = 0; df < 4; df++) {
            #pragma unroll
            for (int ks = 0; ks < 2; ks++) {
                const int vb = (df * 16 + l15) * 72 + ks * 32 + g * 4;
                uint2 v0 = *(const uint2*)&Vc[vb];
                uint2 v1 = *(const uint2*)&Vc[vb + 16];
                union { short8 s; uint4 u; } vv;
                vv.u.x = v0.x; vv.u.y = v0.y; vv.u.z = v1.x; vv.u.w = v1.y;
                #pragma unroll
                for (int mf = 0; mf < 2; mf++)
                    of[mf][df] = mfma_bf16(pa[mf][ks], vv.s, of[mf][df]);
            }
        }
        __builtin_amdgcn_s_setprio(0);
    };

    short8 kA[2], vA[2], kB[2], vB[2];
    load_tile(0, kA, vA);
    if (nt > 1) load_tile(1, kB, vB);
    write_tile(0, kA, vA);
    __syncthreads();

    for (int t = 0; t < nt; t += 2) {
        if (t + 2 < nt) load_tile(t + 2, kA, vA);
        compute_tile(t, Kl[0], Vt[0]);
        write_tile(1, kB, vB);
        __syncthreads();
        if (t + 3 < nt) load_tile(t + 3, kB, vB);
        compute_tile(t + 1, Kl[1], Vt[1]);
        if (t + 2 < nt) write_tile(0, kA, vA);
        __syncthreads();
    }

    // epilogue: O /= l, store attn (b, s, H) bf16
    #pragma unroll
    for (int mf = 0; mf < 2; mf++) {
        #pragma unroll
        for (int r = 0; r < 4; r++) {
            float lr = __shfl(lsum[mf], g * 4 + r, 64);
            float inv = 1.0f / lr;
            int q = q0 + wq + mf * 16 + g * 4 + r;
            #pragma unroll
            for (int df = 0; df < 4; df++)
                attn[((size_t)bb * SEQ + q) * HID + hh * 64 + df * 16 + l15] =
                    f2bf(of[mf][df][r] * inv);
        }
    }
}

// ---------------------------------------------------------------------------
// Kernel 3: out = attn @ w_out (M=4096, N=1024, K=1024), 2-phase pipelined
// double-buffer (same as kernel 1), fp32 output.
// ---------------------------------------------------------------------------
__global__ __launch_bounds__(256) void out_proj_kernel(
    const ushort* __restrict__ attn,    // (4096,1024) bf16
    const ushort* __restrict__ woutT,   // (1024,1024) bf16 (N,K)
    float* __restrict__ out)
{
    __shared__ ushort Al[2][128 * 32];
    __shared__ ushort Bl[2][128 * 32];
    const int tid  = threadIdx.x;
    const int lane = tid & 63;
    const int wv   = tid >> 6;
    const int g    = lane >> 4;
    const int l15  = lane & 15;

    const int lin  = blockIdx.x + 8 * blockIdx.y;   // 0..255
    const int xcd  = lin & 7;
    const int slot = lin >> 3;                      // 0..31
    const int cxi  = xcd & 1, cyi = xcd >> 1;
    const int sx   = slot & 3, sy = slot >> 2;      // 4x8
    const int n0   = (cxi * 4 + sx) * 128;
    const int m0   = (cyi * 8 + sy) * 128;

    const int wr = (wv >> 1) * 64;
    const int wc = (wv & 1) * 64;
    const int rowl = lane >> 2;
    const int kcol = (lane & 3) * 8;

    floatx4 acc[4][4];
    #pragma unroll
    for (int a = 0; a < 4; a++)
        #pragma unroll
        for (int bq = 0; bq < 4; bq++)
            acc[a][bq] = floatx4{0.f, 0.f, 0.f, 0.f};

    const ushort* ga = attn  + (size_t)(m0 + wv * 32 + rowl) * 1024 + kcol;
    const ushort* gb = woutT + (size_t)(n0 + wv * 32 + rowl) * 1024 + kcol;
    const int lofs = wv * 1024;

    gload16(ga,             &Al[0][lofs]);
    gload16(ga + 16 * 1024, &Al[0][lofs + 512]);
    gload16(gb,             &Bl[0][lofs]);
    gload16(gb + 16 * 1024, &Bl[0][lofs + 512]);
    asm volatile("s_waitcnt vmcnt(0)" ::: "memory");
    __builtin_amdgcn_s_barrier();

    for (int it = 0; it < 32; it++) {
        const int cur = it & 1;
        if (it + 1 < 32) {
            const int k0 = (it + 1) * 32;
            const int nxt = cur ^ 1;
            gload16(ga + k0,             &Al[nxt][lofs]);
            gload16(ga + k0 + 16 * 1024, &Al[nxt][lofs + 512]);
            gload16(gb + k0,             &Bl[nxt][lofs]);
            gload16(gb + k0 + 16 * 1024, &Bl[nxt][lofs + 512]);
        }
        short8 af[4], bfr[4];
        #pragma unroll
        for (int fm = 0; fm < 4; fm++)
            af[fm] = *(const short8*)&Al[cur][(wr + fm * 16 + l15) * 32 + g * 8];
        #pragma unroll
        for (int fn = 0; fn < 4; fn++)
            bfr[fn] = *(const short8*)&Bl[cur][(wc + fn * 16 + l15) * 32 + g * 8];
        #pragma unroll
        for (int fm = 0; fm < 4; fm++)
            #pragma unroll
            for (int fn = 0; fn < 4; fn++)
                acc[fm][fn] = mfma_bf16(af[fm], bfr[fn], acc[fm][fn]);
        asm volatile("s_waitcnt vmcnt(0)" ::: "memory");
        __builtin_amdgcn_s_barrier();
    }
    #pragma unroll
    for (int fm = 0; fm < 4; fm++)
        #pragma unroll
        for (int fn = 0; fn < 4; fn++)
            #pragma unroll
            for (int r = 0; r < 4; r++) {
                int row = m0 + wr + fm * 16 + g * 4 + r;
                int col = n0 + wc + fn * 16 + l15;
                out[(size_t)row * 1024 + col] = acc[fm][fn][r];
            }
}

// ---------------------------------------------------------------------------
extern "C" void kernel_launch(void* const* d_in, const int* in_sizes, int n_in,
                              void* d_out, int out_size, void* d_ws, size_t ws_size,
                              hipStream_t stream)
{
    const float* hidden = (const float*)d_in[0];
    const float* wqkv   = (const float*)d_in[1];
    const float* wout   = (const float*)d_in[2];
    float* out = (float*)d_out;

    const size_t NELEM = (size_t)2 * SEQ * HID;   // 4,194,304
    ushort* Qb    = (ushort*)d_ws;
    ushort* Kb    = Qb + NELEM;
    ushort* Vb    = Kb + NELEM;
    ushort* hbf   = Vb + NELEM;                   // hidden bf16; later reused as attn
    ushort* wqkvT = hbf + NELEM;                  // 3072*1024
    ushort* woutT = wqkvT + (size_t)3072 * 1024;  // 1024*1024
    ushort* attnb = hbf;                          // alias: lifetime disjoint

    convert_bf16_kernel<<<2048, 256, 0, stream>>>(hidden, hbf, (int)NELEM);
    transpose_bf16_kernel<<<dim3(48, 16), 256, 0, stream>>>(wqkv, wqkvT, 1024, 3072);
    transpose_bf16_kernel<<<dim3(16, 16), 256, 0, stream>>>(wout, woutT, 1024, 1024);
    qkv_rope_kernel<<<dim3(24, 32), 256, 0, stream>>>(hbf, wqkvT, Qb, Kb, Vb);
    attn_kernel<<<dim3(16, NHEADS, 2), 256, 0, stream>>>(Qb, Kb, Vb, attnb);
    out_proj_kernel<<<dim3(8, 32), 256, 0, stream>>>(attnb, woutT, out);
}

// Round 9
// 129.870 us; speedup vs baseline: 2.6425x; 1.1173x over previous
//
#include <hip/hip_runtime.h>

#define SEQ   2048
#define NHEADS 16
#define HDIM  64
#define HID   1024
#define ROT   32

typedef __attribute__((ext_vector_type(8))) short  short8;
typedef __attribute__((ext_vector_type(4))) float  floatx4;

__device__ __forceinline__ ushort f2bf(float f) {
    union { float f; uint u; } v; v.f = f;
    uint x = v.u;
    uint r = (x + 0x7FFFu + ((x >> 16) & 1u)) >> 16;
    return (ushort)r;
}

__device__ __forceinline__ float fexp2(float x) {
    return __builtin_amdgcn_exp2f(x);     // v_exp_f32 directly
}

__device__ __forceinline__ floatx4 mfma_bf16(short8 a, short8 b, floatx4 c) {
    return __builtin_amdgcn_mfma_f32_16x16x32_bf16(a, b, c, 0, 0, 0);
}

__device__ __forceinline__ void gload16(const ushort* g, ushort* l) {
    __builtin_amdgcn_global_load_lds(
        (const __attribute__((address_space(1))) void*)g,
        (__attribute__((address_space(3))) void*)l, 16, 0, 0);
}

// ---------------------------------------------------------------------------
// Pre-pass A: fp32 -> bf16 elementwise (hidden)
// ---------------------------------------------------------------------------
__global__ __launch_bounds__(256) void convert_bf16_kernel(
    const float* __restrict__ src, ushort* __restrict__ dst, int n)
{
    int i = (blockIdx.x * 256 + threadIdx.x) * 8;
    if (i >= n) return;
    float4 a = *(const float4*)(src + i);
    float4 b = *(const float4*)(src + i + 4);
    short8 v;
    v[0] = (short)f2bf(a.x); v[1] = (short)f2bf(a.y);
    v[2] = (short)f2bf(a.z); v[3] = (short)f2bf(a.w);
    v[4] = (short)f2bf(b.x); v[5] = (short)f2bf(b.y);
    v[6] = (short)f2bf(b.z); v[7] = (short)f2bf(b.w);
    *(short8*)(dst + i) = v;
}

// ---------------------------------------------------------------------------
// Pre-pass B: fp32 (K,N) -> bf16 (N,K) transpose-convert. Tile 64x64.
// ---------------------------------------------------------------------------
__global__ __launch_bounds__(256) void transpose_bf16_kernel(
    const float* __restrict__ src, ushort* __restrict__ dst, int K, int N)
{
    __shared__ ushort Tl[64 * 68];
    const int k0 = blockIdx.y * 64, n0 = blockIdx.x * 64;
    const int tid = threadIdx.x;
    #pragma unroll
    for (int i = 0; i < 4; i++) {
        int lin = tid + 256 * i;
        int row = lin >> 4;
        int c4  = (lin & 15) * 4;
        float4 v = *(const float4*)(src + (size_t)(k0 + row) * N + n0 + c4);
        uint2 u;
        u.x = (uint)f2bf(v.x) | ((uint)f2bf(v.y) << 16);
        u.y = (uint)f2bf(v.z) | ((uint)f2bf(v.w) << 16);
        *(uint2*)&Tl[row * 68 + c4] = u;
    }
    __syncthreads();
    #pragma unroll
    for (int j = 0; j < 2; j++) {
        int lin = tid + 256 * j;
        int n = lin >> 3, c = lin & 7;
        short8 v;
        #pragma unroll
        for (int u = 0; u < 8; u++) v[u] = (short)Tl[(c * 8 + u) * 68 + n];
        *(short8*)(dst + (size_t)(n0 + n) * K + k0 + c * 8) = v;
    }
}

// ---------------------------------------------------------------------------
// Kernel 1: qkv = hidden @ w_qkv (M=4096, N=3072, K=1024) bf16 inputs.
// 128^2 tile, BK=32, 2-phase pipelined gload_lds double-buffer.
// Fused RoPE + head split. Q pre-scaled by 0.125*log2(e) (exp2-domain
// softmax downstream). Q,K (b,h,s,d); V (b,h,d,s).
// ---------------------------------------------------------------------------
__global__ __launch_bounds__(256) void qkv_rope_kernel(
    const ushort* __restrict__ hbf,     // (4096,1024) bf16
    const ushort* __restrict__ wqkvT,   // (3072,1024) bf16 (N,K)
    ushort* __restrict__ Qb, ushort* __restrict__ Kb, ushort* __restrict__ Vb)
{
    __shared__ ushort Al[2][128 * 32];
    __shared__ ushort Bl[2][128 * 32];
    const int tid  = threadIdx.x;
    const int lane = tid & 63;
    const int wv   = tid >> 6;
    const int g    = lane >> 4;
    const int l15  = lane & 15;

    const int lin  = blockIdx.x + 24 * blockIdx.y;  // 0..767
    const int xcd  = lin & 7;
    const int slot = lin >> 3;                      // 0..95
    const int cxi  = xcd & 1, cyi = xcd >> 1;
    const int sx   = slot % 12, sy = slot / 12;     // 12x8
    const int n0   = (cxi * 12 + sx) * 128;
    const int m0   = (cyi * 8 + sy) * 128;

    const int wr = (wv >> 1) * 64;
    const int wc = (wv & 1) * 64;
    const int rowl = lane >> 2;
    const int kcol = (lane & 3) * 8;

    floatx4 acc[4][4];
    #pragma unroll
    for (int a = 0; a < 4; a++)
        #pragma unroll
        for (int bq = 0; bq < 4; bq++)
            acc[a][bq] = floatx4{0.f, 0.f, 0.f, 0.f};

    const ushort* ga = hbf   + (size_t)(m0 + wv * 32 + rowl) * 1024 + kcol;
    const ushort* gb = wqkvT + (size_t)(n0 + wv * 32 + rowl) * 1024 + kcol;
    const int lofs = wv * 1024;

    gload16(ga,             &Al[0][lofs]);
    gload16(ga + 16 * 1024, &Al[0][lofs + 512]);
    gload16(gb,             &Bl[0][lofs]);
    gload16(gb + 16 * 1024, &Bl[0][lofs + 512]);
    asm volatile("s_waitcnt vmcnt(0)" ::: "memory");
    __builtin_amdgcn_s_barrier();

    for (int it = 0; it < 32; it++) {
        const int cur = it & 1;
        if (it + 1 < 32) {
            const int k0 = (it + 1) * 32;
            const int nxt = cur ^ 1;
            gload16(ga + k0,             &Al[nxt][lofs]);
            gload16(ga + k0 + 16 * 1024, &Al[nxt][lofs + 512]);
            gload16(gb + k0,             &Bl[nxt][lofs]);
            gload16(gb + k0 + 16 * 1024, &Bl[nxt][lofs + 512]);
        }
        short8 af[4], bfr[4];
        #pragma unroll
        for (int fm = 0; fm < 4; fm++)
            af[fm] = *(const short8*)&Al[cur][(wr + fm * 16 + l15) * 32 + g * 8];
        #pragma unroll
        for (int fn = 0; fn < 4; fn++)
            bfr[fn] = *(const short8*)&Bl[cur][(wc + fn * 16 + l15) * 32 + g * 8];
        #pragma unroll
        for (int fm = 0; fm < 4; fm++)
            #pragma unroll
            for (int fn = 0; fn < 4; fn++)
                acc[fm][fn] = mfma_bf16(af[fm], bfr[fn], acc[fm][fn]);
        asm volatile("s_waitcnt vmcnt(0)" ::: "memory");
        __builtin_amdgcn_s_barrier();
    }

    #pragma unroll
    for (int fn = 0; fn < 4; fn++) {
        const int c    = n0 + wc + fn * 16 + l15;
        const int mp   = c / 384;
        const int rem  = c - mp * 384;
        const int tsel = rem >> 7;                    // 0=q 1=k 2=v
        const int j    = (rem >> 6) & 1;
        const int d    = rem & 63;
        const int head = mp * 2 + j;
        ushort* basep = (tsel == 0) ? Qb : (tsel == 1) ? Kb : Vb;
        const bool rope = (tsel < 2) && (d < ROT);
        // Q carries 1/sqrt(64) * log2(e) so attention uses exp2 directly
        const float qscale = (tsel == 0) ? 0.18033688011112042f : 1.0f;
        float freq = 0.f;
        if (rope) {
            freq = exp2f((float)(d >> 1) * -0.830482023721841f);
        }
        #pragma unroll
        for (int fm = 0; fm < 4; fm++) {
            #pragma unroll
            for (int r = 0; r < 4; r++) {
                int row = m0 + wr + fm * 16 + g * 4 + r;
                int bb  = row >> 11;
                int s   = row & 2047;
                float val = acc[fm][fn][r];
                float pv  = __shfl_xor(val, 1, 64);
                float outv = val;
                if (rope) {
                    float ang = (float)s * freq;
                    float sn, cs;
                    __sincosf(ang, &sn, &cs);
                    outv = ((d & 1) == 0) ? (val * cs - pv * sn)
                                          : (val * cs + pv * sn);
                }
                outv *= qscale;
                size_t off;
                if (tsel == 2)
                    off = ((size_t)(bb * NHEADS + head) * HDIM + d) * SEQ + s;
                else
                    off = ((size_t)(bb * NHEADS + head) * SEQ + s) * HDIM + d;
                basep[off] = f2bf(outv);
            }
        }
    }
}

// ---------------------------------------------------------------------------
// Kernel 2: flash attention, causal. 512 threads = 8 waves x 16 q-rows
// (Q tile 128), KV tiles 64. Complementary-qb pairing; 2-deep register
// prefetch + LDS double-buffer; exp2-domain softmax with per-lane defer-max
// (cross-lane reduces only on rescale) and epilogue-deferred l-sum.
// ---------------------------------------------------------------------------
__global__ __launch_bounds__(512, 4) void attn_kernel(
    const ushort* __restrict__ Qb, const ushort* __restrict__ Kb,
    const ushort* __restrict__ Vb, ushort* __restrict__ attn)
{
    __shared__ ushort Kl[2][64 * 72];      // [key][d], stride 72
    __shared__ ushort Vt[2][64 * 72];      // [d][key], stride 72

    const int tid  = threadIdx.x;
    const int lane = tid & 63;
    const int wv   = tid >> 6;             // 0..7
    const int g    = lane >> 4;
    const int l15  = lane & 15;

    const int l    = blockIdx.x + 16 * blockIdx.y + 256 * blockIdx.z;
    const int half = l >> 8;
    const int xx   = l & 15;
    const int hh   = (l >> 4) & 15;
    const int qb   = half ? xx : 15 - xx;
    const int bb   = half;

    const int q0 = qb * 128;
    const int wq = wv * 16;
    const size_t kvbase = (size_t)(bb * NHEADS + hh) * SEQ * HDIM;

    const int srow = tid >> 3;             // 0..63 staging row
    const int sch  = (tid & 7) * 8;        // staging col (ushort)

    short8 qreg[2];
    #pragma unroll
    for (int ks = 0; ks < 2; ks++)
        qreg[ks] = *(const short8*)(Qb + kvbase +
            (size_t)(q0 + wq + l15) * HDIM + ks * 32 + g * 8);

    float m = -__builtin_inff();
    float lsum = 0.f;                      // per-lane partial (16 keys/row)
    floatx4 of[4];
    #pragma unroll
    for (int df = 0; df < 4; df++) of[df] = floatx4{0.f, 0.f, 0.f, 0.f};

    const int nt = 2 * qb + 2;             // always even

    auto load_tile = [&](int tt, short8& kr, short8& vr) {
        const int kv = tt * 64;
        kr = *(const short8*)(Kb + kvbase + (size_t)(kv + srow) * HDIM + sch);
        vr = *(const short8*)(Vb + kvbase + (size_t)srow * SEQ + kv + sch);
    };
    auto write_tile = [&](int buf, short8& kr, short8& vr) {
        *(short8*)&Kl[buf][srow * 72 + sch] = kr;
        *(short8*)&Vt[buf][srow * 72 + sch] = vr;
    };
    auto compute_tile = [&](int t, const ushort* Kc, const ushort* Vc) {
        const int kv0 = t * 64;
        if (kv0 > q0 + wq + 15) return;    // fully-masked for this wave
        // QK^T (swapped): sf[kf], lane l15 = q-row, key = kv0 + kf*16 + g*4 + r
        floatx4 sf[4];
        __builtin_amdgcn_s_setprio(1);
        #pragma unroll
        for (int kf = 0; kf < 4; kf++) {
            short8 kr0 = *(const short8*)&Kc[(kf * 16 + l15) * 72 + g * 8];
            short8 kr1 = *(const short8*)&Kc[(kf * 16 + l15) * 72 + 32 + g * 8];
            floatx4 s = floatx4{0.f, 0.f, 0.f, 0.f};
            s = mfma_bf16(kr0, qreg[0], s);
            s = mfma_bf16(kr1, qreg[1], s);
            sf[kf] = s;
        }
        __builtin_amdgcn_s_setprio(0);

        const bool diag = (kv0 + 63 > q0 + wq);   // wave-uniform
        const int qg = q0 + wq + l15;
        float tmax = -__builtin_inff();
        if (diag) {
            #pragma unroll
            for (int kf = 0; kf < 4; kf++) {
                #pragma unroll
                for (int r = 0; r < 4; r++) {
                    int key = kv0 + kf * 16 + g * 4 + r;
                    float x = sf[kf][r];
                    if (key > qg) x = -1e9f;
                    sf[kf][r] = x;
                    tmax = fmaxf(tmax, x);
                }
            }
        } else {
            #pragma unroll
            for (int kf = 0; kf < 4; kf++)
                #pragma unroll
                for (int r = 0; r < 4; r++)
                    tmax = fmaxf(tmax, sf[kf][r]);
        }
        // per-lane defer-max: no cross-lane traffic in the common case
        if (!__all(tmax <= m + 8.0f)) {
            tmax = fmaxf(tmax, __shfl_xor(tmax, 16, 64));
            tmax = fmaxf(tmax, __shfl_xor(tmax, 32, 64));
            float mn = fmaxf(m, tmax);
            float f  = fexp2(m - mn);
            m = mn;
            lsum *= f;
            #pragma unroll
            for (int r = 0; r < 4; r++) {
                float fr = __shfl(f, g * 4 + r, 64);
                #pragma unroll
                for (int df = 0; df < 4; df++)
                    of[df][r] *= fr;
            }
        }
        float rs = 0.f;
        #pragma unroll
        for (int kf = 0; kf < 4; kf++) {
            #pragma unroll
            for (int r = 0; r < 4; r++) {
                float p = fexp2(sf[kf][r] - m);
                sf[kf][r] = p;
                rs += p;
            }
        }
        lsum += rs;
        // pack P into lane-local A-frags via v_cvt_pk_bf16_f32
        short8 pa[2];
        #pragma unroll
        for (int ks = 0; ks < 2; ks++) {
            union { short8 s; uint u[4]; } pu;
            #pragma unroll
            for (int w = 0; w < 4; w++) {
                const int kf = 2 * ks + (w >> 1);
                float lo = sf[kf][(w & 1) * 2 + 0];
                float hi = sf[kf][(w & 1) * 2 + 1];
                asm("v_cvt_pk_bf16_f32 %0, %1, %2"
                    : "=v"(pu.u[w]) : "v"(lo), "v"(hi));
            }
            pa[ks] = pu.s;
        }
        // PV
        __builtin_amdgcn_s_setprio(1);
        #pragma unroll
        for (int df = 0; df < 4; df++) {
            #pragma unroll
            for (int ks = 0; ks < 2; ks++) {
                const int vb = (df * 16 + l15) * 72 + ks * 32 + g * 4;
                uint2 v0 = *(const uint2*)&Vc[vb];
                uint2 v1 = *(const uint2*)&Vc[vb + 16];
                union { short8 s; uint4 u; } vv;
                vv.u.x = v0.x; vv.u.y = v0.y; vv.u.z = v1.x; vv.u.w = v1.y;
                of[df] = mfma_bf16(pa[ks], vv.s, of[df]);
            }
        }
        __builtin_amdgcn_s_setprio(0);
    };

    short8 kA, vA, kB, vB;
    load_tile(0, kA, vA);
    if (nt > 1) load_tile(1, kB, vB);
    write_tile(0, kA, vA);
    __syncthreads();

    for (int t = 0; t < nt; t += 2) {
        if (t + 2 < nt) load_tile(t + 2, kA, vA);
        compute_tile(t, Kl[0], Vt[0]);
        write_tile(1, kB, vB);
        __syncthreads();
        if (t + 3 < nt) load_tile(t + 3, kB, vB);
        compute_tile(t + 1, Kl[1], Vt[1]);
        if (t + 2 < nt) write_tile(0, kA, vA);
        __syncthreads();
    }

    // epilogue: reduce l across g-lanes once, O /= l, store attn (b,s,H) bf16
    lsum += __shfl_xor(lsum, 16, 64);
    lsum += __shfl_xor(lsum, 32, 64);
    #pragma unroll
    for (int r = 0; r < 4; r++) {
        float lr = __shfl(lsum, g * 4 + r, 64);
        float inv = 1.0f / lr;
        int q = q0 + wq + g * 4 + r;
        #pragma unroll
        for (int df = 0; df < 4; df++)
            attn[((size_t)bb * SEQ + q) * HID + hh * 64 + df * 16 + l15] =
                f2bf(of[df][r] * inv);
    }
}

// ---------------------------------------------------------------------------
// Kernel 3: out = attn @ w_out (M=4096, N=1024, K=1024), 2-phase pipelined
// double-buffer, fp32 output.
// ---------------------------------------------------------------------------
__global__ __launch_bounds__(256) void out_proj_kernel(
    const ushort* __restrict__ attn,    // (4096,1024) bf16
    const ushort* __restrict__ woutT,   // (1024,1024) bf16 (N,K)
    float* __restrict__ out)
{
    __shared__ ushort Al[2][128 * 32];
    __shared__ ushort Bl[2][128 * 32];
    const int tid  = threadIdx.x;
    const int lane = tid & 63;
    const int wv   = tid >> 6;
    const int g    = lane >> 4;
    const int l15  = lane & 15;

    const int lin  = blockIdx.x + 8 * blockIdx.y;   // 0..255
    const int xcd  = lin & 7;
    const int slot = lin >> 3;                      // 0..31
    const int cxi  = xcd & 1, cyi = xcd >> 1;
    const int sx   = slot & 3, sy = slot >> 2;      // 4x8
    const int n0   = (cxi * 4 + sx) * 128;
    const int m0   = (cyi * 8 + sy) * 128;

    const int wr = (wv >> 1) * 64;
    const int wc = (wv & 1) * 64;
    const int rowl = lane >> 2;
    const int kcol = (lane & 3) * 8;

    floatx4 acc[4][4];
    #pragma unroll
    for (int a = 0; a < 4; a++)
        #pragma unroll
        for (int bq = 0; bq < 4; bq++)
            acc[a][bq] = floatx4{0.f, 0.f, 0.f, 0.f};

    const ushort* ga = attn  + (size_t)(m0 + wv * 32 + rowl) * 1024 + kcol;
    const ushort* gb = woutT + (size_t)(n0 + wv * 32 + rowl) * 1024 + kcol;
    const int lofs = wv * 1024;

    gload16(ga,             &Al[0][lofs]);
    gload16(ga + 16 * 1024, &Al[0][lofs + 512]);
    gload16(gb,             &Bl[0][lofs]);
    gload16(gb + 16 * 1024, &Bl[0][lofs + 512]);
    asm volatile("s_waitcnt vmcnt(0)" ::: "memory");
    __builtin_amdgcn_s_barrier();

    for (int it = 0; it < 32; it++) {
        const int cur = it & 1;
        if (it + 1 < 32) {
            const int k0 = (it + 1) * 32;
            const int nxt = cur ^ 1;
            gload16(ga + k0,             &Al[nxt][lofs]);
            gload16(ga + k0 + 16 * 1024, &Al[nxt][lofs + 512]);
            gload16(gb + k0,             &Bl[nxt][lofs]);
            gload16(gb + k0 + 16 * 1024, &Bl[nxt][lofs + 512]);
        }
        short8 af[4], bfr[4];
        #pragma unroll
        for (int fm = 0; fm < 4; fm++)
            af[fm] = *(const short8*)&Al[cur][(wr + fm * 16 + l15) * 32 + g * 8];
        #pragma unroll
        for (int fn = 0; fn < 4; fn++)
            bfr[fn] = *(const short8*)&Bl[cur][(wc + fn * 16 + l15) * 32 + g * 8];
        #pragma unroll
        for (int fm = 0; fm < 4; fm++)
            #pragma unroll
            for (int fn = 0; fn < 4; fn++)
                acc[fm][fn] = mfma_bf16(af[fm], bfr[fn], acc[fm][fn]);
        asm volatile("s_waitcnt vmcnt(0)" ::: "memory");
        __builtin_amdgcn_s_barrier();
    }
    #pragma unroll
    for (int fm = 0; fm < 4; fm++)
        #pragma unroll
        for (int fn = 0; fn < 4; fn++)
            #pragma unroll
            for (int r = 0; r < 4; r++) {
                int row = m0 + wr + fm * 16 + g * 4 + r;
                int col = n0 + wc + fn * 16 + l15;
                out[(size_t)row * 1024 + col] = acc[fm][fn][r];
            }
}

// ---------------------------------------------------------------------------
extern "C" void kernel_launch(void* const* d_in, const int* in_sizes, int n_in,
                              void* d_out, int out_size, void* d_ws, size_t ws_size,
                              hipStream_t stream)
{
    const float* hidden = (const float*)d_in[0];
    const float* wqkv   = (const float*)d_in[1];
    const float* wout   = (const float*)d_in[2];
    float* out = (float*)d_out;

    const size_t NELEM = (size_t)2 * SEQ * HID;   // 4,194,304
    ushort* Qb    = (ushort*)d_ws;
    ushort* Kb    = Qb + NELEM;
    ushort* Vb    = Kb + NELEM;
    ushort* hbf   = Vb + NELEM;                   // hidden bf16; later reused as attn
    ushort* wqkvT = hbf + NELEM;                  // 3072*1024
    ushort* woutT = wqkvT + (size_t)3072 * 1024;  // 1024*1024
    ushort* attnb = hbf;                          // alias: lifetime disjoint

    convert_bf16_kernel<<<2048, 256, 0, stream>>>(hidden, hbf, (int)NELEM);
    transpose_bf16_kernel<<<dim3(48, 16), 256, 0, stream>>>(wqkv, wqkvT, 1024, 3072);
    transpose_bf16_kernel<<<dim3(16, 16), 256, 0, stream>>>(wout, woutT, 1024, 1024);
    qkv_rope_kernel<<<dim3(24, 32), 256, 0, stream>>>(hbf, wqkvT, Qb, Kb, Vb);
    attn_kernel<<<dim3(16, NHEADS, 2), 512, 0, stream>>>(Qb, Kb, Vb, attnb);
    out_proj_kernel<<<dim3(8, 32), 256, 0, stream>>>(attnb, woutT, out);
}